// Round 7
// baseline (2311.895 us; speedup 1.0000x reference)
//
#include <hip/hip_runtime.h>
#include <hip/hip_cooperative_groups.h>

namespace cg = cooperative_groups;

// GATv2 stack on MI355X. fp32 throughout (no fp32 MFMA on CDNA4 -> vector ALU).
// R6: single cooperative mega-kernel (grid.sync between phases) to kill the
// ~7us/dispatch launch+tail overhead measured via the R5 A/B. Gat = R4 form
// (full 64-lane wave per dst, online softmax, unroll-4, 2 chains). Fallback
// multi-dispatch path if cooperative launch is unavailable.

static __device__ __forceinline__ float lrelu(float x, float s) {
    return x > 0.f ? x : s * x;
}

struct Params {
    const float *x, *eat;
    const int *src, *dst, *mask, *batch;
    const float *g0_Wl, *g0_bl, *g0_Wr, *g0_br, *g0_We, *g0_att, *g0_bias;
    const float *bn_g, *bn_b;
    const float *m_Wl, *m_bl, *m_Wr, *m_br, *m_We, *m_att, *m_bias;
    const float *f_Wl, *f_bl, *f_Wr, *f_br, *f_We, *f_att, *f_bias;
    const float *s_Wl, *s_bl, *s_Wr, *s_br, *s_We, *s_att, *s_bias;
    int *cnt, *rank, *row_ptr, *bsum, *csr_src;
    float *csr_ea, *xl, *xr, *hbuf, *fin;
    double *stats;
    float *sums, *cnts;
    float *out_mus, *out_sat;
    int N, E, G, ITER;
};

// ---- device phase helpers (called from mega kernel and reused logic) ----

__device__ __forceinline__ void gat_phase(const float* __restrict__ xl,
                                          const float* __restrict__ xr,
                                          const int* __restrict__ row_ptr,
                                          const int* __restrict__ csr_src,
                                          const float* __restrict__ csr_ea,
                                          const float* __restrict__ We,
                                          const float* __restrict__ att,
                                          const float* __restrict__ bias,
                                          float* __restrict__ out,
                                          int n, int relu, int gtid, int GT) {
    const int w = gtid >> 6, NW = GT >> 6;
    const int lane = gtid & 63;
    const float we0 = We[lane], we1 = We[64 + lane];
    const float av = att[lane];
    const float bi = bias[lane];
    for (int d = w; d < n; d += NW) {
        const int p0 = __builtin_amdgcn_readfirstlane(row_ptr[d]);
        const int p1 = __builtin_amdgcn_readfirstlane(row_ptr[d + 1]);
        const float xrv = xr[(size_t)d * 64 + lane];
        float mx0 = -3.0e38f, den0 = 0.f, acc0 = 0.f;
        float mx1 = -3.0e38f, den1 = 0.f, acc1 = 0.f;
        for (int p = p0; p < p1; p += 4) {
            int q1 = min(p + 1, p1 - 1), q2 = min(p + 2, p1 - 1), q3 = min(p + 3, p1 - 1);
            int s0 = csr_src[p], s1 = csr_src[q1], s2 = csr_src[q2], s3 = csr_src[q3];
            float2 e0 = *(const float2*)(csr_ea + 2 * (size_t)p);
            float2 e1 = *(const float2*)(csr_ea + 2 * (size_t)q1);
            float2 e2 = *(const float2*)(csr_ea + 2 * (size_t)q2);
            float2 e3 = *(const float2*)(csr_ea + 2 * (size_t)q3);
            float x0 = xl[(size_t)s0 * 64 + lane];
            float x1 = xl[(size_t)s1 * 64 + lane];
            float x2 = xl[(size_t)s2 * 64 + lane];
            float x3 = xl[(size_t)s3 * 64 + lane];
            {
                float tv = lrelu(x0 + xrv + e0.x * we0 + e0.y * we1, 0.2f) * av;
                tv += __shfl_xor(tv, 1); tv += __shfl_xor(tv, 2);
                float nm = fmaxf(mx0, tv);
                float sc = __expf(mx0 - nm), wv = __expf(tv - nm);
                den0 = den0 * sc + wv; acc0 = acc0 * sc + wv * x0; mx0 = nm;
            }
            {
                float tv = lrelu(x1 + xrv + e1.x * we0 + e1.y * we1, 0.2f) * av;
                tv += __shfl_xor(tv, 1); tv += __shfl_xor(tv, 2);
                if (p + 1 >= p1) tv = -__builtin_inff();
                float nm = fmaxf(mx1, tv);
                float sc = __expf(mx1 - nm), wv = __expf(tv - nm);
                den1 = den1 * sc + wv; acc1 = acc1 * sc + wv * x1; mx1 = nm;
            }
            {
                float tv = lrelu(x2 + xrv + e2.x * we0 + e2.y * we1, 0.2f) * av;
                tv += __shfl_xor(tv, 1); tv += __shfl_xor(tv, 2);
                if (p + 2 >= p1) tv = -__builtin_inff();
                float nm = fmaxf(mx0, tv);
                float sc = __expf(mx0 - nm), wv = __expf(tv - nm);
                den0 = den0 * sc + wv; acc0 = acc0 * sc + wv * x2; mx0 = nm;
            }
            {
                float tv = lrelu(x3 + xrv + e3.x * we0 + e3.y * we1, 0.2f) * av;
                tv += __shfl_xor(tv, 1); tv += __shfl_xor(tv, 2);
                if (p + 3 >= p1) tv = -__builtin_inff();
                float nm = fmaxf(mx1, tv);
                float sc = __expf(mx1 - nm), wv = __expf(tv - nm);
                den1 = den1 * sc + wv; acc1 = acc1 * sc + wv * x3; mx1 = nm;
            }
        }
        float nm = fmaxf(mx0, mx1);
        float sc0 = __expf(mx0 - nm), sc1 = __expf(mx1 - nm);
        float o = (acc0 * sc0 + acc1 * sc1) / (den0 * sc0 + den1 * sc1) + bi;
        if (relu) o = lrelu(o, 0.01f);
        out[(size_t)d * 64 + lane] = o;
    }
}

// ---------------- the cooperative mega kernel ----------------

__launch_bounds__(512, 4)
__global__ void k_mega(Params P) {
    cg::grid_group grid = cg::this_grid();
    const int NB = gridDim.x, BT = blockDim.x;       // NB in {256,512}, BT=512
    const int bid = blockIdx.x, thr = threadIdx.x;
    const int gtid = bid * BT + thr, GT = NB * BT;
    __shared__ float smem[8260];

    // phase 0: zero scratch
    for (int i = gtid; i < P.N; i += GT) P.cnt[i] = 0;
    if (gtid < 128) P.stats[gtid] = 0.0;
    if (gtid < P.G) { P.sums[gtid] = 0.f; P.cnts[gtid] = 0.f; }
    grid.sync();

    // phase 1: degree + rank
    for (int e = gtid; e < P.E; e += GT) P.rank[e] = atomicAdd(&P.cnt[P.dst[e]], 1);
    grid.sync();

    // phase 2: exclusive scan of (cnt+1) -> row_ptr. thread gtid owns element gtid.
    {
        int* s = (int*)smem;
        int idx = gtid;
        int val = (idx < P.N) ? P.cnt[idx] + 1 : 0;
        s[thr] = val;
        __syncthreads();
        for (int off = 1; off < BT; off <<= 1) {
            int v = (thr >= off) ? s[thr - off] : 0;
            __syncthreads();
            s[thr] += v;
            __syncthreads();
        }
        int incl = s[thr];
        if (idx <= P.N) P.row_ptr[idx] = incl - val;   // local exclusive
        if (thr == BT - 1) P.bsum[bid] = incl;         // block total
    }
    grid.sync();
    if (bid == 0) {
        int* s = (int*)smem;
        int v = (thr < NB) ? P.bsum[thr] : 0;
        s[thr] = v;
        __syncthreads();
        for (int off = 1; off < BT; off <<= 1) {
            int u = (thr >= off) ? s[thr - off] : 0;
            __syncthreads();
            s[thr] += u;
            __syncthreads();
        }
        if (thr < NB) P.bsum[thr] = s[thr] - v;        // exclusive block prefix
    }
    grid.sync();
    if (gtid <= P.N) P.row_ptr[gtid] += P.bsum[bid];
    grid.sync();

    // phase 3: scatter edges into CSR
    for (int e = gtid; e < P.E; e += GT) {
        int pos = P.row_ptr[P.dst[e]] + P.rank[e];
        P.csr_src[pos] = P.src[e];
        P.csr_ea[2 * (size_t)pos] = P.eat[2 * (size_t)e];
        P.csr_ea[2 * (size_t)pos + 1] = P.eat[2 * (size_t)e + 1];
    }
    grid.sync();

    // phase 4: self loops (attr = segment mean)
    for (int i = gtid; i < P.N; i += GT) {
        int p0 = P.row_ptr[i], p1 = P.row_ptr[i + 1];
        float s0 = 0.f, s1 = 0.f;
        for (int p = p0; p < p1 - 1; ++p) {
            s0 += P.csr_ea[2 * (size_t)p];
            s1 += P.csr_ea[2 * (size_t)p + 1];
        }
        float c = fmaxf((float)(p1 - 1 - p0), 1.f);
        P.csr_src[p1 - 1] = i;
        P.csr_ea[2 * (size_t)(p1 - 1)] = s0 / c;
        P.csr_ea[2 * (size_t)(p1 - 1) + 1] = s1 / c;
    }
    grid.sync();

    // phase 5: proj0  x[N,2] @ W[2,64]
    for (int idx = gtid; idx < P.N * 64; idx += GT) {
        int i = idx >> 6, c = idx & 63;
        float x0 = P.x[2 * i], x1 = P.x[2 * i + 1];
        P.xl[idx] = x0 * P.g0_Wl[c] + x1 * P.g0_Wl[64 + c] + P.g0_bl[c];
        P.xr[idx] = x0 * P.g0_Wr[c] + x1 * P.g0_Wr[64 + c] + P.g0_br[c];
    }
    grid.sync();

    // phase 6: gat layer 0 -> hbuf
    gat_phase(P.xl, P.xr, P.row_ptr, P.csr_src, P.csr_ea,
              P.g0_We, P.g0_att, P.g0_bias, P.hbuf, P.N, 0, gtid, GT);
    grid.sync();

    // phase 7: bn stats (8192 threads: c = gtid&63, row-stride 128)
    if (gtid < 64 * 128) {
        int c = gtid & 63, r0 = gtid >> 6;
        double s = 0.0, s2 = 0.0;
        for (int i = r0; i < P.N; i += 128) {
            float v = P.hbuf[(size_t)i * 64 + c];
            s += v;
            s2 += (double)v * v;
        }
        atomicAdd(&P.stats[c], s);
        atomicAdd(&P.stats[64 + c], s2);
    }
    grid.sync();

    // phase 8: bn apply + leaky relu
    for (int idx = gtid; idx < P.N * 64; idx += GT) {
        int c = idx & 63;
        double mu = P.stats[c] / P.N;
        double var = P.stats[64 + c] / P.N - mu * mu;
        float rs = (float)(1.0 / sqrt(var + 1e-5));
        float v = (P.hbuf[idx] - (float)mu) * rs * P.bn_g[c] + P.bn_b[c];
        P.hbuf[idx] = lrelu(v, 0.01f);
    }
    grid.sync();

    // phases 9..: main layers
    for (int l = 0; l < P.ITER; ++l) {
        // proj: hbuf @ {Wl,Wr} -> xl, xr  (weights staged in LDS)
        {
            const float* Wl = P.m_Wl + (size_t)l * 4096;
            const float* Wr = P.m_Wr + (size_t)l * 4096;
            const float* bl = P.m_bl + l * 64;
            const float* br = P.m_br + l * 64;
            float* wsl = smem;
            float* wsr = smem + 4096;
            for (int i = thr; i < 4096; i += BT) { wsl[i] = Wl[i]; wsr[i] = Wr[i]; }
            __syncthreads();
            int rg = thr >> 2, cg4 = (thr & 3) << 4;
            for (int tile = bid; tile * 128 < P.N; tile += NB) {
                int r = tile * 128 + rg;
                if (r < P.N) {
                    float accl[16], accr[16];
#pragma unroll
                    for (int j = 0; j < 16; ++j) { accl[j] = 0.f; accr[j] = 0.f; }
                    for (int k0 = 0; k0 < 64; k0 += 4) {
                        float4 v = *(const float4*)(P.hbuf + (size_t)r * 64 + k0);
                        float hk[4] = {v.x, v.y, v.z, v.w};
#pragma unroll
                        for (int kk = 0; kk < 4; ++kk) {
                            const float* wl = wsl + (k0 + kk) * 64 + cg4;
                            const float* wr = wsr + (k0 + kk) * 64 + cg4;
#pragma unroll
                            for (int j = 0; j < 16; ++j) {
                                accl[j] += hk[kk] * wl[j];
                                accr[j] += hk[kk] * wr[j];
                            }
                        }
                    }
                    float* ol = P.xl + (size_t)r * 64 + cg4;
                    float* orr = P.xr + (size_t)r * 64 + cg4;
#pragma unroll
                    for (int j = 0; j < 16; ++j) {
                        ol[j] = accl[j] + bl[cg4 + j];
                        orr[j] = accr[j] + br[cg4 + j];
                    }
                }
            }
            __syncthreads();
        }
        grid.sync();
        gat_phase(P.xl, P.xr, P.row_ptr, P.csr_src, P.csr_ea,
                  P.m_We + l * 128, P.m_att + l * 64, P.m_bias + l * 64,
                  P.hbuf, P.N, 1, gtid, GT);
        grid.sync();
    }

    // final projections: packed[i] = [f_xl(16) | s_xl(16) | f_xr(16) | s_xr(16)] -> xl
    {
        float* ws = smem;          // [64][64]
        float* bs = smem + 4096;   // [64]
        for (int i = thr; i < 1024; i += BT) {
            int k = i >> 4, j = i & 15;
            ws[k * 64 + j] = P.f_Wl[i];
            ws[k * 64 + 16 + j] = P.s_Wl[i];
            ws[k * 64 + 32 + j] = P.f_Wr[i];
            ws[k * 64 + 48 + j] = P.s_Wr[i];
        }
        if (thr < 16) {
            bs[thr] = P.f_bl[thr]; bs[16 + thr] = P.s_bl[thr];
            bs[32 + thr] = P.f_br[thr]; bs[48 + thr] = P.s_br[thr];
        }
        __syncthreads();
        int rg = thr >> 2, cg4 = (thr & 3) << 4;
        for (int tile = bid; tile * 128 < P.N; tile += NB) {
            int r = tile * 128 + rg;
            if (r < P.N) {
                float acc[16];
#pragma unroll
                for (int j = 0; j < 16; ++j) acc[j] = 0.f;
                for (int k0 = 0; k0 < 64; k0 += 4) {
                    float4 v = *(const float4*)(P.hbuf + (size_t)r * 64 + k0);
                    float hk[4] = {v.x, v.y, v.z, v.w};
#pragma unroll
                    for (int kk = 0; kk < 4; ++kk) {
                        const float* wrow = ws + (k0 + kk) * 64 + cg4;
#pragma unroll
                        for (int j = 0; j < 16; ++j) acc[j] += hk[kk] * wrow[j];
                    }
                }
                float* o = P.xl + (size_t)r * 64 + cg4;
#pragma unroll
                for (int j = 0; j < 16; ++j) o[j] = acc[j] + bs[cg4 + j];
            }
        }
        __syncthreads();
    }
    grid.sync();

    // final two GAT layers (H=16, C=1), fused: half-wave per dst
    {
        int hw = gtid >> 5, NH = GT >> 5;
        int lh = thr & 31;
        int hh = lh & 15, sel = lh >> 4;
        const float* We = sel ? P.s_We : P.f_We;
        float we0 = We[hh], we1 = We[16 + hh];
        float av = (sel ? P.s_att : P.f_att)[hh];
        float fb = P.f_bias[0], sb = P.s_bias[0];
        for (int d = hw; d < P.N; d += NH) {
            const int p0 = P.row_ptr[d], p1 = P.row_ptr[d + 1];
            float xrv = P.xl[(size_t)d * 64 + 32 + sel * 16 + hh];
            int xli = sel * 16 + hh;
            float mx0 = -3.0e38f, den0 = 0.f, acc0 = 0.f;
            float mx1 = -3.0e38f, den1 = 0.f, acc1 = 0.f;
            for (int p = p0; p < p1; p += 4) {
                int q1 = min(p + 1, p1 - 1), q2 = min(p + 2, p1 - 1), q3 = min(p + 3, p1 - 1);
                int s0 = P.csr_src[p], s1 = P.csr_src[q1], s2 = P.csr_src[q2], s3 = P.csr_src[q3];
                float2 e0 = *(const float2*)(P.csr_ea + 2 * (size_t)p);
                float2 e1 = *(const float2*)(P.csr_ea + 2 * (size_t)q1);
                float2 e2 = *(const float2*)(P.csr_ea + 2 * (size_t)q2);
                float2 e3 = *(const float2*)(P.csr_ea + 2 * (size_t)q3);
                float x0 = P.xl[(size_t)s0 * 64 + xli];
                float x1 = P.xl[(size_t)s1 * 64 + xli];
                float x2 = P.xl[(size_t)s2 * 64 + xli];
                float x3 = P.xl[(size_t)s3 * 64 + xli];
                {
                    float t = lrelu(x0 + xrv + e0.x * we0 + e0.y * we1, 0.2f) * av;
                    float nm = fmaxf(mx0, t);
                    float sc = __expf(mx0 - nm), wv = __expf(t - nm);
                    den0 = den0 * sc + wv; acc0 = acc0 * sc + wv * x0; mx0 = nm;
                }
                {
                    float t = lrelu(x1 + xrv + e1.x * we0 + e1.y * we1, 0.2f) * av;
                    if (p + 1 >= p1) t = -__builtin_inff();
                    float nm = fmaxf(mx1, t);
                    float sc = __expf(mx1 - nm), wv = __expf(t - nm);
                    den1 = den1 * sc + wv; acc1 = acc1 * sc + wv * x1; mx1 = nm;
                }
                {
                    float t = lrelu(x2 + xrv + e2.x * we0 + e2.y * we1, 0.2f) * av;
                    if (p + 2 >= p1) t = -__builtin_inff();
                    float nm = fmaxf(mx0, t);
                    float sc = __expf(mx0 - nm), wv = __expf(t - nm);
                    den0 = den0 * sc + wv; acc0 = acc0 * sc + wv * x2; mx0 = nm;
                }
                {
                    float t = lrelu(x3 + xrv + e3.x * we0 + e3.y * we1, 0.2f) * av;
                    if (p + 3 >= p1) t = -__builtin_inff();
                    float nm = fmaxf(mx1, t);
                    float sc = __expf(mx1 - nm), wv = __expf(t - nm);
                    den1 = den1 * sc + wv; acc1 = acc1 * sc + wv * x3; mx1 = nm;
                }
            }
            float nm = fmaxf(mx0, mx1);
            float sc0 = __expf(mx0 - nm), sc1 = __expf(mx1 - nm);
            float val = (acc0 * sc0 + acc1 * sc1) / (den0 * sc0 + den1 * sc1);
#pragma unroll
            for (int w = 1; w < 16; w <<= 1) val += __shfl_xor(val, w);
            if ((thr & 15) == 0) {
                float o = val * (1.f / 16.f) + (sel ? sb : fb);
                if (sel) P.out_mus[d] = o; else P.fin[d] = o;
            }
        }
    }
    grid.sync();

    // sat: masked per-graph mean of fin (batch sorted -> wave-segmented)
    {
        int i = gtid;
        int lane = thr & 63;
        int g = (i < P.N) ? P.batch[i] : -1;
        float c = (i < P.N && P.mask[i] == 0) ? 1.f : 0.f;
        float v = (c > 0.f) ? P.fin[i] : 0.f;
#pragma unroll
        for (int off = 1; off < 64; off <<= 1) {
            float v2 = __shfl_down(v, off);
            float c2 = __shfl_down(c, off);
            int g2 = __shfl_down(g, off);
            if (lane + off < 64 && g2 == g) { v += v2; c += c2; }
        }
        int gprev = __shfl_up(g, 1);
        bool head = (lane == 0) || (gprev != g);
        if (head && g >= 0 && c > 0.f) {
            atomicAdd(&P.sums[g], v);
            atomicAdd(&P.cnts[g], c);
        }
    }
    grid.sync();
    if (bid == 0 && thr < P.G) P.out_sat[thr] = P.sums[thr] / fmaxf(P.cnts[thr], 1.f);
}

// ---------------- fallback kernels (R4 structure) ----------------

__global__ void k_degree(const int* __restrict__ dst, int* __restrict__ cnt,
                         int* __restrict__ rank, int E) {
    int e = blockIdx.x * blockDim.x + threadIdx.x;
    if (e >= E) return;
    rank[e] = atomicAdd(&cnt[dst[e]], 1);
}

__launch_bounds__(1024)
__global__ void k_rowptr(const int* __restrict__ cnt, int* __restrict__ row_ptr, int n) {
    __shared__ int tot[1024];
    int t = threadIdx.x;
    int chunk = (n + 1023) >> 10;
    int b = min(t * chunk, n), e = min(b + chunk, n);
    int s = 0;
    for (int i = b; i < e; ++i) s += cnt[i] + 1;
    tot[t] = s;
    __syncthreads();
    for (int off = 1; off < 1024; off <<= 1) {
        int v = (t >= off) ? tot[t - off] : 0;
        __syncthreads();
        tot[t] += v;
        __syncthreads();
    }
    int run = (t > 0) ? tot[t - 1] : 0;
    for (int i = b; i < e; ++i) { row_ptr[i] = run; run += cnt[i] + 1; }
    if (t == 1023) row_ptr[n] = run;
}

__global__ void k_scatter(const int* __restrict__ src, const int* __restrict__ dst,
                          const float* __restrict__ ea, const int* __restrict__ rank,
                          const int* __restrict__ row_ptr,
                          int* __restrict__ csr_src, float* __restrict__ csr_ea, int E) {
    int e = blockIdx.x * blockDim.x + threadIdx.x;
    if (e >= E) return;
    int pos = row_ptr[dst[e]] + rank[e];
    csr_src[pos] = src[e];
    csr_ea[2 * (size_t)pos] = ea[2 * (size_t)e];
    csr_ea[2 * (size_t)pos + 1] = ea[2 * (size_t)e + 1];
}

__global__ void k_selfloop(const int* __restrict__ row_ptr,
                           int* __restrict__ csr_src, float* __restrict__ csr_ea, int n) {
    int i = blockIdx.x * blockDim.x + threadIdx.x;
    if (i >= n) return;
    int p0 = row_ptr[i], p1 = row_ptr[i + 1];
    float s0 = 0.f, s1 = 0.f;
    for (int p = p0; p < p1 - 1; ++p) {
        s0 += csr_ea[2 * (size_t)p];
        s1 += csr_ea[2 * (size_t)p + 1];
    }
    float c = fmaxf((float)(p1 - 1 - p0), 1.f);
    csr_src[p1 - 1] = i;
    csr_ea[2 * (size_t)(p1 - 1)] = s0 / c;
    csr_ea[2 * (size_t)(p1 - 1) + 1] = s1 / c;
}

__global__ void k_proj0(const float* __restrict__ x,
                        const float* __restrict__ Wl, const float* __restrict__ bl,
                        const float* __restrict__ Wr, const float* __restrict__ br,
                        float* __restrict__ xl, float* __restrict__ xr, int n) {
    int idx = blockIdx.x * blockDim.x + threadIdx.x;
    if (idx >= n * 64) return;
    int i = idx >> 6, c = idx & 63;
    float x0 = x[2 * i], x1 = x[2 * i + 1];
    xl[idx] = x0 * Wl[c] + x1 * Wl[64 + c] + bl[c];
    xr[idx] = x0 * Wr[c] + x1 * Wr[64 + c] + br[c];
}

__launch_bounds__(256)
__global__ void k_proj64(const float* __restrict__ h,
                         const float* __restrict__ Wl, const float* __restrict__ bl,
                         const float* __restrict__ Wr, const float* __restrict__ br,
                         float* __restrict__ xl, float* __restrict__ xr, int n) {
    __shared__ float wsl[4096], wsr[4096];
    int t = threadIdx.x;
    for (int i = t; i < 4096; i += 256) { wsl[i] = Wl[i]; wsr[i] = Wr[i]; }
    __syncthreads();
    int rg = t >> 2, cg4 = (t & 3) << 4;
    int r0 = blockIdx.x * 128 + rg * 2;
    float accl[2][16], accr[2][16];
#pragma unroll
    for (int r = 0; r < 2; ++r)
#pragma unroll
        for (int j = 0; j < 16; ++j) { accl[r][j] = 0.f; accr[r][j] = 0.f; }
    for (int k0 = 0; k0 < 64; k0 += 4) {
        float hk[2][4];
#pragma unroll
        for (int r = 0; r < 2; ++r) {
            int gr = r0 + r;
            float4 v = (gr < n) ? *(const float4*)(h + (size_t)gr * 64 + k0)
                                : make_float4(0.f, 0.f, 0.f, 0.f);
            hk[r][0] = v.x; hk[r][1] = v.y; hk[r][2] = v.z; hk[r][3] = v.w;
        }
#pragma unroll
        for (int kk = 0; kk < 4; ++kk) {
            const float* wl = wsl + (k0 + kk) * 64 + cg4;
            const float* wr = wsr + (k0 + kk) * 64 + cg4;
#pragma unroll
            for (int r = 0; r < 2; ++r)
#pragma unroll
                for (int j = 0; j < 16; ++j) {
                    accl[r][j] += hk[r][kk] * wl[j];
                    accr[r][j] += hk[r][kk] * wr[j];
                }
        }
    }
#pragma unroll
    for (int r = 0; r < 2; ++r) {
        int gr = r0 + r;
        if (gr < n) {
            float* ol = xl + (size_t)gr * 64 + cg4;
            float* orr = xr + (size_t)gr * 64 + cg4;
#pragma unroll
            for (int j = 0; j < 16; ++j) {
                ol[j] = accl[r][j] + bl[cg4 + j];
                orr[j] = accr[r][j] + br[cg4 + j];
            }
        }
    }
}

__launch_bounds__(256)
__global__ void k_proj_final(const float* __restrict__ h,
                             const float* __restrict__ fWl, const float* __restrict__ fbl,
                             const float* __restrict__ fWr, const float* __restrict__ fbr,
                             const float* __restrict__ sWl, const float* __restrict__ sbl,
                             const float* __restrict__ sWr, const float* __restrict__ sbr,
                             float* __restrict__ packed, int n) {
    __shared__ float ws[4096];
    __shared__ float bs[64];
    int t = threadIdx.x;
    for (int i = t; i < 1024; i += 256) {
        int k = i >> 4, j = i & 15;
        ws[k * 64 + j] = fWl[i];
        ws[k * 64 + 16 + j] = sWl[i];
        ws[k * 64 + 32 + j] = fWr[i];
        ws[k * 64 + 48 + j] = sWr[i];
    }
    if (t < 16) { bs[t] = fbl[t]; bs[16 + t] = sbl[t]; bs[32 + t] = fbr[t]; bs[48 + t] = sbr[t]; }
    __syncthreads();
    int rg = t >> 2, cg4 = (t & 3) << 4;
    int r0 = blockIdx.x * 256 + rg * 4;
    float acc[4][16];
#pragma unroll
    for (int r = 0; r < 4; ++r)
#pragma unroll
        for (int j = 0; j < 16; ++j) acc[r][j] = 0.f;
    for (int k0 = 0; k0 < 64; k0 += 4) {
        float hk[4][4];
#pragma unroll
        for (int r = 0; r < 4; ++r) {
            int gr = r0 + r;
            float4 v = (gr < n) ? *(const float4*)(h + (size_t)gr * 64 + k0)
                                : make_float4(0.f, 0.f, 0.f, 0.f);
            hk[r][0] = v.x; hk[r][1] = v.y; hk[r][2] = v.z; hk[r][3] = v.w;
        }
#pragma unroll
        for (int kk = 0; kk < 4; ++kk) {
            const float* wrow = ws + (k0 + kk) * 64 + cg4;
#pragma unroll
            for (int r = 0; r < 4; ++r)
#pragma unroll
                for (int j = 0; j < 16; ++j) acc[r][j] += hk[r][kk] * wrow[j];
        }
    }
#pragma unroll
    for (int r = 0; r < 4; ++r) {
        int gr = r0 + r;
        if (gr < n) {
            float* o = packed + (size_t)gr * 64 + cg4;
#pragma unroll
            for (int j = 0; j < 16; ++j) o[j] = acc[r][j] + bs[cg4 + j];
        }
    }
}

__launch_bounds__(256)
__global__ void k_gat(const float* __restrict__ xl, const float* __restrict__ xr,
                      const int* __restrict__ row_ptr, const int* __restrict__ csr_src,
                      const float* __restrict__ csr_ea,
                      const float* __restrict__ We, const float* __restrict__ att,
                      const float* __restrict__ bias,
                      float* __restrict__ out, int n, int relu) {
    int gtid = blockIdx.x * blockDim.x + threadIdx.x;
    if ((gtid >> 6) >= n) return;
    gat_phase(xl, xr, row_ptr, csr_src, csr_ea, We, att, bias, out, n, relu,
              gtid, n * 64);  // stride covers exactly once
}

__launch_bounds__(256)
__global__ void k_gat_final(const float* __restrict__ packed,
                            const int* __restrict__ row_ptr, const int* __restrict__ csr_src,
                            const float* __restrict__ csr_ea,
                            const float* __restrict__ fWe, const float* __restrict__ sWe,
                            const float* __restrict__ fatt, const float* __restrict__ satt,
                            const float* __restrict__ fbias, const float* __restrict__ sbias,
                            float* __restrict__ fin, float* __restrict__ mus, int n) {
    int hw = (blockIdx.x * blockDim.x + threadIdx.x) >> 5;
    if (hw >= n) return;
    int l = threadIdx.x & 31;
    int hh = l & 15, sel = l >> 4;
    const int d = hw;
    const int p0 = row_ptr[d], p1 = row_ptr[d + 1];
    const float* We = sel ? sWe : fWe;
    float we0 = We[hh], we1 = We[16 + hh];
    float av = (sel ? satt : fatt)[hh];
    float xrv = packed[(size_t)d * 64 + 32 + sel * 16 + hh];
    int xli = sel * 16 + hh;
    float mx0 = -3.0e38f, den0 = 0.f, acc0 = 0.f;
    float mx1 = -3.0e38f, den1 = 0.f, acc1 = 0.f;
    for (int p = p0; p < p1; p += 2) {
        int q1 = min(p + 1, p1 - 1);
        int s0 = csr_src[p], s1 = csr_src[q1];
        float2 e0 = *(const float2*)(csr_ea + 2 * (size_t)p);
        float2 e1 = *(const float2*)(csr_ea + 2 * (size_t)q1);
        float x0 = packed[(size_t)s0 * 64 + xli];
        float x1 = packed[(size_t)s1 * 64 + xli];
        {
            float t = lrelu(x0 + xrv + e0.x * we0 + e0.y * we1, 0.2f) * av;
            float nm = fmaxf(mx0, t);
            float sc = __expf(mx0 - nm), wv = __expf(t - nm);
            den0 = den0 * sc + wv; acc0 = acc0 * sc + wv * x0; mx0 = nm;
        }
        {
            float t = lrelu(x1 + xrv + e1.x * we0 + e1.y * we1, 0.2f) * av;
            if (p + 1 >= p1) t = -__builtin_inff();
            float nm = fmaxf(mx1, t);
            float sc = __expf(mx1 - nm), wv = __expf(t - nm);
            den1 = den1 * sc + wv; acc1 = acc1 * sc + wv * x1; mx1 = nm;
        }
    }
    float nm = fmaxf(mx0, mx1);
    float s0 = __expf(mx0 - nm), s1 = __expf(mx1 - nm);
    float val = (acc0 * s0 + acc1 * s1) / (den0 * s0 + den1 * s1);
#pragma unroll
    for (int w = 1; w < 16; w <<= 1) val += __shfl_xor(val, w);
    if ((threadIdx.x & 15) == 0) {
        float o = val * (1.f / 16.f) + (sel ? sbias[0] : fbias[0]);
        if (sel) mus[d] = o; else fin[d] = o;
    }
}

__global__ void k_bnstats(const float* __restrict__ h, double* __restrict__ stats, int n) {
    int c = threadIdx.x & 63;
    int s0 = blockIdx.x * (blockDim.x >> 6) + (threadIdx.x >> 6);
    int ns = gridDim.x * (blockDim.x >> 6);
    double s = 0.0, s2 = 0.0;
    for (int i = s0; i < n; i += ns) {
        float v = h[(size_t)i * 64 + c];
        s += v;
        s2 += (double)v * v;
    }
    atomicAdd(&stats[c], s);
    atomicAdd(&stats[64 + c], s2);
}

__global__ void k_bnapply(float* __restrict__ h, const double* __restrict__ stats,
                          const float* __restrict__ gamma, const float* __restrict__ beta, int n) {
    int idx = blockIdx.x * blockDim.x + threadIdx.x;
    if (idx >= n * 64) return;
    int c = idx & 63;
    double mu = stats[c] / n;
    double var = stats[64 + c] / n - mu * mu;
    float rs = (float)(1.0 / sqrt(var + 1e-5));
    float v = (h[idx] - (float)mu) * rs * gamma[c] + beta[c];
    h[idx] = lrelu(v, 0.01f);
}

__global__ void k_sat_acc(const float* __restrict__ fin, const int* __restrict__ mask,
                          const int* __restrict__ batch,
                          float* __restrict__ sums, float* __restrict__ cnts, int n) {
    int i = blockIdx.x * blockDim.x + threadIdx.x;
    int lane = threadIdx.x & 63;
    int g = (i < n) ? batch[i] : -1;
    float c = (i < n && mask[i] == 0) ? 1.f : 0.f;
    float v = (c > 0.f) ? fin[i] : 0.f;
#pragma unroll
    for (int off = 1; off < 64; off <<= 1) {
        float v2 = __shfl_down(v, off);
        float c2 = __shfl_down(c, off);
        int g2 = __shfl_down(g, off);
        if (lane + off < 64 && g2 == g) { v += v2; c += c2; }
    }
    int gprev = __shfl_up(g, 1);
    bool head = (lane == 0) || (gprev != g);
    if (head && g >= 0 && c > 0.f) {
        atomicAdd(&sums[g], v);
        atomicAdd(&cnts[g], c);
    }
}

__global__ void k_sat_fin(const float* __restrict__ sums, const float* __restrict__ cnts,
                          float* __restrict__ out, int g) {
    int i = threadIdx.x;
    if (i < g) out[i] = sums[i] / fmaxf(cnts[i], 1.f);
}

// ---------------- host ----------------

extern "C" void kernel_launch(void* const* d_in, const int* in_sizes, int n_in,
                              void* d_out, int out_size, void* d_ws, size_t ws_size,
                              hipStream_t stream) {
    Params P;
    P.x = (const float*)d_in[0];
    P.eat = (const float*)d_in[1];
    const int* ei = (const int*)d_in[2];
    P.mask = (const int*)d_in[3];
    P.batch = (const int*)d_in[4];
    P.g0_Wl = (const float*)d_in[5];  P.g0_bl = (const float*)d_in[6];
    P.g0_Wr = (const float*)d_in[7];  P.g0_br = (const float*)d_in[8];
    P.g0_We = (const float*)d_in[9];  P.g0_att = (const float*)d_in[10];
    P.g0_bias = (const float*)d_in[11];
    P.bn_g = (const float*)d_in[12];  P.bn_b = (const float*)d_in[13];
    P.m_Wl = (const float*)d_in[14];  P.m_bl = (const float*)d_in[15];
    P.m_Wr = (const float*)d_in[16];  P.m_br = (const float*)d_in[17];
    P.m_We = (const float*)d_in[18];  P.m_att = (const float*)d_in[19];
    P.m_bias = (const float*)d_in[20];
    P.f_Wl = (const float*)d_in[21];  P.f_bl = (const float*)d_in[22];
    P.f_Wr = (const float*)d_in[23];  P.f_br = (const float*)d_in[24];
    P.f_We = (const float*)d_in[25];  P.f_att = (const float*)d_in[26];
    P.f_bias = (const float*)d_in[27];
    P.s_Wl = (const float*)d_in[28];  P.s_bl = (const float*)d_in[29];
    P.s_Wr = (const float*)d_in[30];  P.s_br = (const float*)d_in[31];
    P.s_We = (const float*)d_in[32];  P.s_att = (const float*)d_in[33];
    P.s_bias = (const float*)d_in[34];

    P.N = in_sizes[3];
    P.E = in_sizes[1] / 2;
    P.G = out_size - P.N;
    P.ITER = in_sizes[14] / 4096;
    const int ET = P.E + P.N;
    P.src = ei;
    P.dst = ei + P.E;

    char* wsb = (char*)d_ws;
    size_t off = 0;
    auto alloc = [&](size_t b) { void* p = wsb + off; off = (off + b + 255) & ~(size_t)255; return p; };
    P.cnt = (int*)alloc((size_t)P.N * 4);
    P.stats = (double*)alloc(128 * 8);
    P.sums = (float*)alloc((size_t)P.G * 4);
    P.cnts = (float*)alloc((size_t)P.G * 4);
    size_t zero_bytes = off;
    P.rank = (int*)alloc((size_t)P.E * 4);
    P.row_ptr = (int*)alloc((size_t)(P.N + 1) * 4);
    P.bsum = (int*)alloc(1024 * 4);
    P.csr_src = (int*)alloc((size_t)ET * 4);
    P.csr_ea = (float*)alloc((size_t)ET * 8);
    P.xl = (float*)alloc((size_t)P.N * 256);
    P.xr = (float*)alloc((size_t)P.N * 256);
    P.hbuf = (float*)alloc((size_t)P.N * 256);
    P.fin = (float*)alloc((size_t)P.N * 4);
    (void)ws_size; (void)n_in;

    float* outv = (float*)d_out;
    P.out_mus = outv;
    P.out_sat = outv + P.N;

    // try the cooperative mega-kernel
    int maxb = 0;
    hipError_t qerr = hipOccupancyMaxActiveBlocksPerMultiprocessor(&maxb, (const void*)k_mega, 512, 0);
    bool coop_ok = (qerr == hipSuccess && maxb >= 1);
    if (coop_ok) {
        int nb = (maxb >= 2) ? 512 : 256;
        void* args[] = {&P};
        hipError_t lerr = hipLaunchCooperativeKernel((void*)k_mega, dim3(nb), dim3(512),
                                                     args, 0, stream);
        if (lerr == hipSuccess) return;
    }

    // fallback: multi-dispatch path (R4 structure)
    hipMemsetAsync(d_ws, 0, zero_bytes, stream);
    const int tb = 256;
    k_degree<<<(P.E + tb - 1) / tb, tb, 0, stream>>>(P.dst, P.cnt, P.rank, P.E);
    k_rowptr<<<1, 1024, 0, stream>>>(P.cnt, P.row_ptr, P.N);
    k_scatter<<<(P.E + tb - 1) / tb, tb, 0, stream>>>(P.src, P.dst, P.eat, P.rank, P.row_ptr,
                                                      P.csr_src, P.csr_ea, P.E);
    k_selfloop<<<(P.N + tb - 1) / tb, tb, 0, stream>>>(P.row_ptr, P.csr_src, P.csr_ea, P.N);
    k_proj0<<<(P.N * 64 + tb - 1) / tb, tb, 0, stream>>>(P.x, P.g0_Wl, P.g0_bl, P.g0_Wr, P.g0_br,
                                                         P.xl, P.xr, P.N);
    k_gat<<<(P.N * 64 + tb - 1) / tb, tb, 0, stream>>>(P.xl, P.xr, P.row_ptr, P.csr_src, P.csr_ea,
                                                       P.g0_We, P.g0_att, P.g0_bias, P.hbuf, P.N, 0);
    k_bnstats<<<128, 256, 0, stream>>>(P.hbuf, P.stats, P.N);
    k_bnapply<<<(P.N * 64 + tb - 1) / tb, tb, 0, stream>>>(P.hbuf, P.stats, P.bn_g, P.bn_b, P.N);
    int gp = (P.N + 127) / 128;
    for (int l = 0; l < P.ITER; ++l) {
        k_proj64<<<gp, 256, 0, stream>>>(P.hbuf, P.m_Wl + (size_t)l * 4096, P.m_bl + l * 64,
                                         P.m_Wr + (size_t)l * 4096, P.m_br + l * 64,
                                         P.xl, P.xr, P.N);
        k_gat<<<(P.N * 64 + tb - 1) / tb, tb, 0, stream>>>(P.xl, P.xr, P.row_ptr, P.csr_src,
                                                           P.csr_ea, P.m_We + l * 128,
                                                           P.m_att + l * 64, P.m_bias + l * 64,
                                                           P.hbuf, P.N, 1);
    }
    k_proj_final<<<(P.N + 255) / 256, 256, 0, stream>>>(P.hbuf, P.f_Wl, P.f_bl, P.f_Wr, P.f_br,
                                                        P.s_Wl, P.s_bl, P.s_Wr, P.s_br, P.xl, P.N);
    k_gat_final<<<(P.N * 32 + tb - 1) / tb, tb, 0, stream>>>(P.xl, P.row_ptr, P.csr_src, P.csr_ea,
                                                             P.f_We, P.s_We, P.f_att, P.s_att,
                                                             P.f_bias, P.s_bias, P.fin, outv, P.N);
    k_sat_acc<<<(P.N + tb - 1) / tb, tb, 0, stream>>>(P.fin, P.mask, P.batch, P.sums, P.cnts, P.N);
    k_sat_fin<<<1, 64, 0, stream>>>(P.sums, P.cnts, outv + P.N, P.G);
}

// Round 8
// 862.883 us; speedup vs baseline: 2.6793x; 2.6793x over previous
//
#include <hip/hip_runtime.h>

// GATv2 stack on MI355X. fp32 throughout (no fp32 MFMA on CDNA4 -> vector ALU).
// R7: revert to R4 multi-dispatch structure (R6 coop mega-kernel regressed 2.8x:
// grid.sync ~80us on CDNA4 + halved occupancy). Changes vs R4:
//  - 4-way sub-counter degree (quarters atomic same-address contention)
//  - degree fused with proj0 (independent work, one dispatch)
//  - bn-apply folded into layer-0 projection (saves a 13MB pass + dispatch)
//  - gat back to unroll-4 / 2-chain (unroll-8 was neutral, costs VGPRs)

static __device__ __forceinline__ float lrelu(float x, float s) {
    return x > 0.f ? x : s * x;
}

// ---------------- fused degree + proj0 ----------------
// threads [0,E): rank/degree atomics into 4 sub-counters
// threads [E, E+N*64): x[N,2] @ W[2,64] + b for both l and r
__global__ void k_build0(const int* __restrict__ dst, int* __restrict__ cnt4,
                         int* __restrict__ rank, int E,
                         const float* __restrict__ x,
                         const float* __restrict__ Wl, const float* __restrict__ bl,
                         const float* __restrict__ Wr, const float* __restrict__ br,
                         float* __restrict__ xl, float* __restrict__ xr, int n) {
    int idx = blockIdx.x * blockDim.x + threadIdx.x;
    if (idx < E) {
        rank[idx] = atomicAdd(&cnt4[4 * dst[idx] + (idx & 3)], 1);
    } else {
        int t = idx - E;
        if (t < n * 64) {
            int i = t >> 6, c = t & 63;
            float x0 = x[2 * i], x1 = x[2 * i + 1];
            xl[t] = x0 * Wl[c] + x1 * Wl[64 + c] + bl[c];
            xr[t] = x0 * Wr[c] + x1 * Wr[64 + c] + br[c];
        }
    }
}

// scan of (deg+1) -> row_ptr; also emits per-node sub-counter bases
__launch_bounds__(1024)
__global__ void k_rowptr(const int* __restrict__ cnt4, int* __restrict__ row_ptr,
                         int* __restrict__ subbase, int n) {
    __shared__ int tot[1024];
    int t = threadIdx.x;
    int chunk = (n + 1023) >> 10;
    int b = min(t * chunk, n), e = min(b + chunk, n);
    int s = 0;
    for (int i = b; i < e; ++i) {
        int c0 = cnt4[4 * i], c1 = cnt4[4 * i + 1], c2 = cnt4[4 * i + 2], c3 = cnt4[4 * i + 3];
        subbase[4 * i] = 0;
        subbase[4 * i + 1] = c0;
        subbase[4 * i + 2] = c0 + c1;
        subbase[4 * i + 3] = c0 + c1 + c2;
        s += c0 + c1 + c2 + c3 + 1;
    }
    tot[t] = s;
    __syncthreads();
    for (int off = 1; off < 1024; off <<= 1) {
        int v = (t >= off) ? tot[t - off] : 0;
        __syncthreads();
        tot[t] += v;
        __syncthreads();
    }
    int run = (t > 0) ? tot[t - 1] : 0;
    for (int i = b; i < e; ++i) {
        row_ptr[i] = run;
        run += cnt4[4 * i] + cnt4[4 * i + 1] + cnt4[4 * i + 2] + cnt4[4 * i + 3] + 1;
    }
    if (t == 1023) row_ptr[n] = run;
}

__global__ void k_scatter(const int* __restrict__ src, const int* __restrict__ dst,
                          const float* __restrict__ ea, const int* __restrict__ rank,
                          const int* __restrict__ row_ptr, const int* __restrict__ subbase,
                          int* __restrict__ csr_src, float* __restrict__ csr_ea, int E) {
    int e = blockIdx.x * blockDim.x + threadIdx.x;
    if (e >= E) return;
    int d = dst[e];
    int pos = row_ptr[d] + subbase[4 * d + (e & 3)] + rank[e];
    csr_src[pos] = src[e];
    *(float2*)(csr_ea + 2 * (size_t)pos) = *(const float2*)(ea + 2 * (size_t)e);
}

__global__ void k_selfloop(const int* __restrict__ row_ptr,
                           int* __restrict__ csr_src, float* __restrict__ csr_ea, int n) {
    int i = blockIdx.x * blockDim.x + threadIdx.x;
    if (i >= n) return;
    int p0 = row_ptr[i], p1 = row_ptr[i + 1];
    float s0 = 0.f, s1 = 0.f;
    for (int p = p0; p < p1 - 1; ++p) {
        s0 += csr_ea[2 * (size_t)p];
        s1 += csr_ea[2 * (size_t)p + 1];
    }
    float c = fmaxf((float)(p1 - 1 - p0), 1.f);
    csr_src[p1 - 1] = i;
    csr_ea[2 * (size_t)(p1 - 1)] = s0 / c;
    csr_ea[2 * (size_t)(p1 - 1) + 1] = s1 / c;
}

// ---------------- projection (dual W, optional fused BN on input) ----------------
// h[N,64] @ {Wl,Wr} + {bl,br}; if stats!=null, input first mapped through
// lrelu(h*a_c + b_c, 0.01) with a,b from batchnorm stats (layer-0 only).
__launch_bounds__(256)
__global__ void k_proj64(const float* __restrict__ h,
                         const float* __restrict__ Wl, const float* __restrict__ bl,
                         const float* __restrict__ Wr, const float* __restrict__ br,
                         const double* __restrict__ stats,
                         const float* __restrict__ bng, const float* __restrict__ bnb,
                         float* __restrict__ xl, float* __restrict__ xr, int n) {
    __shared__ float wsl[4096], wsr[4096], bna[64], bnbb[64];
    int t = threadIdx.x;
    for (int i = t; i < 4096; i += 256) { wsl[i] = Wl[i]; wsr[i] = Wr[i]; }
    const bool bn = (stats != nullptr);
    if (bn && t < 64) {
        double mu = stats[t] / n;
        double var = stats[64 + t] / n - mu * mu;
        float rs = (float)(1.0 / sqrt(var + 1e-5));
        float a = rs * bng[t];
        bna[t] = a;
        bnbb[t] = bnb[t] - (float)mu * a;
    }
    __syncthreads();
    int rg = t >> 2, cg4 = (t & 3) << 4;
    int r0 = blockIdx.x * 128 + rg * 2;
    float accl[2][16], accr[2][16];
#pragma unroll
    for (int r = 0; r < 2; ++r)
#pragma unroll
        for (int j = 0; j < 16; ++j) { accl[r][j] = 0.f; accr[r][j] = 0.f; }
    for (int k0 = 0; k0 < 64; k0 += 4) {
        float hk[2][4];
#pragma unroll
        for (int r = 0; r < 2; ++r) {
            int gr = r0 + r;
            float4 v = (gr < n) ? *(const float4*)(h + (size_t)gr * 64 + k0)
                                : make_float4(0.f, 0.f, 0.f, 0.f);
            hk[r][0] = v.x; hk[r][1] = v.y; hk[r][2] = v.z; hk[r][3] = v.w;
            if (bn) {
#pragma unroll
                for (int kk = 0; kk < 4; ++kk)
                    hk[r][kk] = lrelu(hk[r][kk] * bna[k0 + kk] + bnbb[k0 + kk], 0.01f);
            }
        }
#pragma unroll
        for (int kk = 0; kk < 4; ++kk) {
            const float* wl = wsl + (k0 + kk) * 64 + cg4;
            const float* wr = wsr + (k0 + kk) * 64 + cg4;
#pragma unroll
            for (int r = 0; r < 2; ++r)
#pragma unroll
                for (int j = 0; j < 16; ++j) {
                    accl[r][j] += hk[r][kk] * wl[j];
                    accr[r][j] += hk[r][kk] * wr[j];
                }
        }
    }
#pragma unroll
    for (int r = 0; r < 2; ++r) {
        int gr = r0 + r;
        if (gr < n) {
            float* ol = xl + (size_t)gr * 64 + cg4;
            float* orr = xr + (size_t)gr * 64 + cg4;
#pragma unroll
            for (int j = 0; j < 16; ++j) {
                ol[j] = accl[r][j] + bl[cg4 + j];
                orr[j] = accr[r][j] + br[cg4 + j];
            }
        }
    }
}

// final projections fused: packed[i][0:16)=f_xl, [16:32)=s_xl, [32:48)=f_xr, [48:64)=s_xr
__launch_bounds__(256)
__global__ void k_proj_final(const float* __restrict__ h,
                             const float* __restrict__ fWl, const float* __restrict__ fbl,
                             const float* __restrict__ fWr, const float* __restrict__ fbr,
                             const float* __restrict__ sWl, const float* __restrict__ sbl,
                             const float* __restrict__ sWr, const float* __restrict__ sbr,
                             float* __restrict__ packed, int n) {
    __shared__ float ws[4096];
    __shared__ float bs[64];
    int t = threadIdx.x;
    for (int i = t; i < 1024; i += 256) {
        int k = i >> 4, j = i & 15;
        ws[k * 64 + j] = fWl[i];
        ws[k * 64 + 16 + j] = sWl[i];
        ws[k * 64 + 32 + j] = fWr[i];
        ws[k * 64 + 48 + j] = sWr[i];
    }
    if (t < 16) { bs[t] = fbl[t]; bs[16 + t] = sbl[t]; bs[32 + t] = fbr[t]; bs[48 + t] = sbr[t]; }
    __syncthreads();
    int rg = t >> 2, cg4 = (t & 3) << 4;
    int r0 = blockIdx.x * 256 + rg * 4;
    float acc[4][16];
#pragma unroll
    for (int r = 0; r < 4; ++r)
#pragma unroll
        for (int j = 0; j < 16; ++j) acc[r][j] = 0.f;
    for (int k0 = 0; k0 < 64; k0 += 4) {
        float hk[4][4];
#pragma unroll
        for (int r = 0; r < 4; ++r) {
            int gr = r0 + r;
            float4 v = (gr < n) ? *(const float4*)(h + (size_t)gr * 64 + k0)
                                : make_float4(0.f, 0.f, 0.f, 0.f);
            hk[r][0] = v.x; hk[r][1] = v.y; hk[r][2] = v.z; hk[r][3] = v.w;
        }
#pragma unroll
        for (int kk = 0; kk < 4; ++kk) {
            const float* wrow = ws + (k0 + kk) * 64 + cg4;
#pragma unroll
            for (int r = 0; r < 4; ++r)
#pragma unroll
                for (int j = 0; j < 16; ++j) acc[r][j] += hk[r][kk] * wrow[j];
        }
    }
#pragma unroll
    for (int r = 0; r < 4; ++r) {
        int gr = r0 + r;
        if (gr < n) {
            float* o = packed + (size_t)gr * 64 + cg4;
#pragma unroll
            for (int j = 0; j < 16; ++j) o[j] = acc[r][j] + bs[cg4 + j];
        }
    }
}

// ---------------- GATv2 attention ----------------
// one wave per dst; lane = head*4 + channel. online softmax, unroll-4, 2 chains.
__launch_bounds__(256)
__global__ void k_gat(const float* __restrict__ xl, const float* __restrict__ xr,
                      const int* __restrict__ row_ptr, const int* __restrict__ csr_src,
                      const float* __restrict__ csr_ea,
                      const float* __restrict__ We, const float* __restrict__ att,
                      const float* __restrict__ bias,
                      float* __restrict__ out, int n, int relu) {
    int wave = (blockIdx.x * blockDim.x + threadIdx.x) >> 6;
    int lane = threadIdx.x & 63;
    if (wave >= n) return;
    const int d = wave;
    const int p0 = __builtin_amdgcn_readfirstlane(row_ptr[d]);
    const int p1 = __builtin_amdgcn_readfirstlane(row_ptr[d + 1]);
    const float we0 = We[lane], we1 = We[64 + lane];
    const float av = att[lane];
    const float xrv = xr[(size_t)d * 64 + lane];

    float mx0 = -3.0e38f, den0 = 0.f, acc0 = 0.f;
    float mx1 = -3.0e38f, den1 = 0.f, acc1 = 0.f;

    auto step = [&](float xv, float2 ea, bool valid, float& mx, float& den, float& acc) {
        float tv = lrelu(xv + xrv + ea.x * we0 + ea.y * we1, 0.2f) * av;
        tv += __shfl_xor(tv, 1);
        tv += __shfl_xor(tv, 2);
        if (!valid) tv = -__builtin_inff();
        float nm = fmaxf(mx, tv);
        float sc = __expf(mx - nm), w = __expf(tv - nm);
        den = den * sc + w;
        acc = acc * sc + w * xv;
        mx = nm;
    };

    for (int p = p0; p < p1; p += 4) {
        int q1 = min(p + 1, p1 - 1), q2 = min(p + 2, p1 - 1), q3 = min(p + 3, p1 - 1);
        int s0 = csr_src[p], s1 = csr_src[q1], s2 = csr_src[q2], s3 = csr_src[q3];
        float2 e0 = *(const float2*)(csr_ea + 2 * (size_t)p);
        float2 e1 = *(const float2*)(csr_ea + 2 * (size_t)q1);
        float2 e2 = *(const float2*)(csr_ea + 2 * (size_t)q2);
        float2 e3 = *(const float2*)(csr_ea + 2 * (size_t)q3);
        float x0 = xl[(size_t)s0 * 64 + lane];
        float x1 = xl[(size_t)s1 * 64 + lane];
        float x2 = xl[(size_t)s2 * 64 + lane];
        float x3 = xl[(size_t)s3 * 64 + lane];
        step(x0, e0, true, mx0, den0, acc0);
        step(x1, e1, p + 1 < p1, mx1, den1, acc1);
        step(x2, e2, p + 2 < p1, mx0, den0, acc0);
        step(x3, e3, p + 3 < p1, mx1, den1, acc1);
    }
    float nm = fmaxf(mx0, mx1);
    float sc0 = __expf(mx0 - nm), sc1 = __expf(mx1 - nm);
    float o = (acc0 * sc0 + acc1 * sc1) / (den0 * sc0 + den1 * sc1) + bias[lane];
    if (relu) o = lrelu(o, 0.01f);
    out[(size_t)d * 64 + lane] = o;
}

// final two H=16,C=1 layers fused: half-wave per dst (0-15 f -> fin, 16-31 s -> mus)
__launch_bounds__(256)
__global__ void k_gat_final(const float* __restrict__ packed,
                            const int* __restrict__ row_ptr, const int* __restrict__ csr_src,
                            const float* __restrict__ csr_ea,
                            const float* __restrict__ fWe, const float* __restrict__ sWe,
                            const float* __restrict__ fatt, const float* __restrict__ satt,
                            const float* __restrict__ fbias, const float* __restrict__ sbias,
                            float* __restrict__ fin, float* __restrict__ mus, int n) {
    int hw = (blockIdx.x * blockDim.x + threadIdx.x) >> 5;
    if (hw >= n) return;
    int l = threadIdx.x & 31;
    int hh = l & 15, sel = l >> 4;
    const int d = hw;
    const int p0 = row_ptr[d], p1 = row_ptr[d + 1];
    const float* We = sel ? sWe : fWe;
    float we0 = We[hh], we1 = We[16 + hh];
    float av = (sel ? satt : fatt)[hh];
    float xrv = packed[(size_t)d * 64 + 32 + sel * 16 + hh];
    int xli = sel * 16 + hh;

    float mx0 = -3.0e38f, den0 = 0.f, acc0 = 0.f;
    float mx1 = -3.0e38f, den1 = 0.f, acc1 = 0.f;

    auto step = [&](float xv, float2 ea, bool valid, float& mx, float& den, float& acc) {
        float t = lrelu(xv + xrv + ea.x * we0 + ea.y * we1, 0.2f) * av;
        if (!valid) t = -__builtin_inff();
        float nm = fmaxf(mx, t);
        float sc = __expf(mx - nm), w = __expf(t - nm);
        den = den * sc + w;
        acc = acc * sc + w * xv;
        mx = nm;
    };

    for (int p = p0; p < p1; p += 4) {
        int q1 = min(p + 1, p1 - 1), q2 = min(p + 2, p1 - 1), q3 = min(p + 3, p1 - 1);
        int s0 = csr_src[p], s1 = csr_src[q1], s2 = csr_src[q2], s3 = csr_src[q3];
        float2 e0 = *(const float2*)(csr_ea + 2 * (size_t)p);
        float2 e1 = *(const float2*)(csr_ea + 2 * (size_t)q1);
        float2 e2 = *(const float2*)(csr_ea + 2 * (size_t)q2);
        float2 e3 = *(const float2*)(csr_ea + 2 * (size_t)q3);
        float x0 = packed[(size_t)s0 * 64 + xli];
        float x1 = packed[(size_t)s1 * 64 + xli];
        float x2 = packed[(size_t)s2 * 64 + xli];
        float x3 = packed[(size_t)s3 * 64 + xli];
        step(x0, e0, true, mx0, den0, acc0);
        step(x1, e1, p + 1 < p1, mx1, den1, acc1);
        step(x2, e2, p + 2 < p1, mx0, den0, acc0);
        step(x3, e3, p + 3 < p1, mx1, den1, acc1);
    }
    float nm = fmaxf(mx0, mx1);
    float s0 = __expf(mx0 - nm), s1 = __expf(mx1 - nm);
    float val = (acc0 * s0 + acc1 * s1) / (den0 * s0 + den1 * s1);
#pragma unroll
    for (int w = 1; w < 16; w <<= 1) val += __shfl_xor(val, w);
    if ((threadIdx.x & 15) == 0) {
        float o = val * (1.f / 16.f) + (sel ? sbias[0] : fbias[0]);
        if (sel) mus[d] = o; else fin[d] = o;
    }
}

// ---------------- batchnorm stats ----------------

__global__ void k_bnstats(const float* __restrict__ h, double* __restrict__ stats, int n) {
    int c = threadIdx.x & 63;
    int s0 = blockIdx.x * (blockDim.x >> 6) + (threadIdx.x >> 6);
    int ns = gridDim.x * (blockDim.x >> 6);
    double s = 0.0, s2 = 0.0;
    for (int i = s0; i < n; i += ns) {
        float v = h[(size_t)i * 64 + c];
        s += v;
        s2 += (double)v * v;
    }
    atomicAdd(&stats[c], s);
    atomicAdd(&stats[64 + c], s2);
}

// ---------------- graph-level mean over masked nodes ----------------

__global__ void k_sat_acc(const float* __restrict__ fin, const int* __restrict__ mask,
                          const int* __restrict__ batch,
                          float* __restrict__ sums, float* __restrict__ cnts, int n) {
    int i = blockIdx.x * blockDim.x + threadIdx.x;
    int lane = threadIdx.x & 63;
    int g = (i < n) ? batch[i] : -1;
    float c = (i < n && mask[i] == 0) ? 1.f : 0.f;
    float v = (c > 0.f) ? fin[i] : 0.f;
#pragma unroll
    for (int off = 1; off < 64; off <<= 1) {
        float v2 = __shfl_down(v, off);
        float c2 = __shfl_down(c, off);
        int g2 = __shfl_down(g, off);
        if (lane + off < 64 && g2 == g) { v += v2; c += c2; }
    }
    int gprev = __shfl_up(g, 1);
    bool head = (lane == 0) || (gprev != g);
    if (head && g >= 0 && c > 0.f) {
        atomicAdd(&sums[g], v);
        atomicAdd(&cnts[g], c);
    }
}

__global__ void k_sat_fin(const float* __restrict__ sums, const float* __restrict__ cnts,
                          float* __restrict__ out, int g) {
    int i = threadIdx.x;
    if (i < g) out[i] = sums[i] / fmaxf(cnts[i], 1.f);
}

// ---------------- host ----------------

extern "C" void kernel_launch(void* const* d_in, const int* in_sizes, int n_in,
                              void* d_out, int out_size, void* d_ws, size_t ws_size,
                              hipStream_t stream) {
    const float* x = (const float*)d_in[0];
    const float* eat = (const float*)d_in[1];
    const int* ei = (const int*)d_in[2];
    const int* mask = (const int*)d_in[3];
    const int* batch = (const int*)d_in[4];
    const float* g0_Wl = (const float*)d_in[5];
    const float* g0_bl = (const float*)d_in[6];
    const float* g0_Wr = (const float*)d_in[7];
    const float* g0_br = (const float*)d_in[8];
    const float* g0_We = (const float*)d_in[9];
    const float* g0_att = (const float*)d_in[10];
    const float* g0_bias = (const float*)d_in[11];
    const float* bn_g = (const float*)d_in[12];
    const float* bn_b = (const float*)d_in[13];
    const float* m_Wl = (const float*)d_in[14];
    const float* m_bl = (const float*)d_in[15];
    const float* m_Wr = (const float*)d_in[16];
    const float* m_br = (const float*)d_in[17];
    const float* m_We = (const float*)d_in[18];
    const float* m_att = (const float*)d_in[19];
    const float* m_bias = (const float*)d_in[20];
    const float* f_Wl = (const float*)d_in[21];
    const float* f_bl = (const float*)d_in[22];
    const float* f_Wr = (const float*)d_in[23];
    const float* f_br = (const float*)d_in[24];
    const float* f_We = (const float*)d_in[25];
    const float* f_att = (const float*)d_in[26];
    const float* f_bias = (const float*)d_in[27];
    const float* s_Wl = (const float*)d_in[28];
    const float* s_bl = (const float*)d_in[29];
    const float* s_Wr = (const float*)d_in[30];
    const float* s_br = (const float*)d_in[31];
    const float* s_We = (const float*)d_in[32];
    const float* s_att = (const float*)d_in[33];
    const float* s_bias = (const float*)d_in[34];

    const int N = in_sizes[3];
    const int E = in_sizes[1] / 2;
    const int G = out_size - N;
    const int ITER = in_sizes[14] / 4096;
    const int ET = E + N;
    const int* srcp = ei;
    const int* dstp = ei + E;

    char* wsb = (char*)d_ws;
    size_t off = 0;
    auto alloc = [&](size_t b) { void* p = wsb + off; off = (off + b + 255) & ~(size_t)255; return p; };
    int* cnt4 = (int*)alloc((size_t)N * 16);
    double* stats = (double*)alloc(128 * 8);
    float* sums = (float*)alloc((size_t)G * 4);
    float* cnts = (float*)alloc((size_t)G * 4);
    size_t zero_bytes = off;
    int* rank = (int*)alloc((size_t)E * 4);
    int* subbase = (int*)alloc((size_t)N * 16);
    int* row_ptr = (int*)alloc((size_t)(N + 1) * 4);
    int* csr_src = (int*)alloc((size_t)ET * 4);
    float* csr_ea = (float*)alloc((size_t)ET * 8);
    float* xl = (float*)alloc((size_t)N * 256);
    float* xr = (float*)alloc((size_t)N * 256);
    float* hbuf = (float*)alloc((size_t)N * 256);
    float* fin = (float*)alloc((size_t)N * 4);
    (void)ws_size; (void)n_in;

    float* outv = (float*)d_out;  // [0,N) = mus, [N,N+G) = sat

    hipMemsetAsync(d_ws, 0, zero_bytes, stream);
    const int tb = 256;
    k_build0<<<(E + N * 64 + tb - 1) / tb, tb, 0, stream>>>(dstp, cnt4, rank, E,
                                                            x, g0_Wl, g0_bl, g0_Wr, g0_br,
                                                            xl, xr, N);
    k_rowptr<<<1, 1024, 0, stream>>>(cnt4, row_ptr, subbase, N);
    k_scatter<<<(E + tb - 1) / tb, tb, 0, stream>>>(srcp, dstp, eat, rank, row_ptr, subbase,
                                                    csr_src, csr_ea, E);
    k_selfloop<<<(N + tb - 1) / tb, tb, 0, stream>>>(row_ptr, csr_src, csr_ea, N);

    k_gat<<<(N * 64 + tb - 1) / tb, tb, 0, stream>>>(xl, xr, row_ptr, csr_src, csr_ea,
                                                     g0_We, g0_att, g0_bias, hbuf, N, 0);
    k_bnstats<<<128, 256, 0, stream>>>(hbuf, stats, N);

    int gp = (N + 127) / 128;
    for (int l = 0; l < ITER; ++l) {
        k_proj64<<<gp, 256, 0, stream>>>(hbuf, m_Wl + (size_t)l * 4096, m_bl + l * 64,
                                         m_Wr + (size_t)l * 4096, m_br + l * 64,
                                         (l == 0) ? stats : nullptr, bn_g, bn_b,
                                         xl, xr, N);
        k_gat<<<(N * 64 + tb - 1) / tb, tb, 0, stream>>>(xl, xr, row_ptr, csr_src, csr_ea,
                                                         m_We + l * 128, m_att + l * 64,
                                                         m_bias + l * 64, hbuf, N, 1);
    }
    k_proj_final<<<(N + 255) / 256, 256, 0, stream>>>(hbuf, f_Wl, f_bl, f_Wr, f_br,
                                                      s_Wl, s_bl, s_Wr, s_br, xl, N);
    k_gat_final<<<(N * 32 + tb - 1) / tb, tb, 0, stream>>>(xl, row_ptr, csr_src, csr_ea,
                                                           f_We, s_We, f_att, s_att,
                                                           f_bias, s_bias, fin, outv, N);
    k_sat_acc<<<(N + tb - 1) / tb, tb, 0, stream>>>(fin, mask, batch, sums, cnts, N);
    k_sat_fin<<<1, 64, 0, stream>>>(sums, cnts, outv + N, G);
}

// Round 9
// 744.759 us; speedup vs baseline: 3.1042x; 1.1586x over previous
//
#include <hip/hip_runtime.h>

// GATv2 stack on MI355X. fp32 throughout (no fp32 MFMA on CDNA4 -> vector ALU).
// R8: replace the single-block ordered prefix scan (127us, serial on 1 CU) with
// wave-aggregated atomic segment allocation (~390 atomics, order-free CSR:
// segments contiguous per node, self-loop last, p1 = start + cnt + 1).
// Keeps R7's fused build0 (degree+proj0) and BN folded into layer-0 proj.

static __device__ __forceinline__ float lrelu(float x, float s) {
    return x > 0.f ? x : s * x;
}

// ---------------- fused degree + proj0 ----------------
__global__ void k_build0(const int* __restrict__ dst, int* __restrict__ cnt,
                         int* __restrict__ rank, int E,
                         const float* __restrict__ x,
                         const float* __restrict__ Wl, const float* __restrict__ bl,
                         const float* __restrict__ Wr, const float* __restrict__ br,
                         float* __restrict__ xl, float* __restrict__ xr, int n) {
    int idx = blockIdx.x * blockDim.x + threadIdx.x;
    if (idx < E) {
        rank[idx] = atomicAdd(&cnt[dst[idx]], 1);
    } else {
        int t = idx - E;
        if (t < n * 64) {
            int i = t >> 6, c = t & 63;
            float x0 = x[2 * i], x1 = x[2 * i + 1];
            xl[t] = x0 * Wl[c] + x1 * Wl[64 + c] + bl[c];
            xr[t] = x0 * Wr[c] + x1 * Wr[64 + c] + br[c];
        }
    }
}

// wave-aggregated segment offset allocation: row_start[i] = cursor alloc of cnt[i]+1
__global__ void k_segoff(const int* __restrict__ cnt, int* __restrict__ row_start,
                         int* __restrict__ cursor, int n) {
    int i = blockIdx.x * blockDim.x + threadIdx.x;
    int lane = threadIdx.x & 63;
    int v = (i < n) ? cnt[i] + 1 : 0;
    int s = v;
#pragma unroll
    for (int off = 1; off < 64; off <<= 1) {
        int t = __shfl_up(s, off);
        if (lane >= off) s += t;
    }
    int wavetot = __shfl(s, 63);
    int base = 0;
    if (lane == 63) base = atomicAdd(cursor, wavetot);
    base = __shfl(base, 63);
    if (i < n) row_start[i] = base + s - v;
}

__global__ void k_scatter(const int* __restrict__ src, const int* __restrict__ dst,
                          const float* __restrict__ ea, const int* __restrict__ rank,
                          const int* __restrict__ row_start,
                          int* __restrict__ csr_src, float* __restrict__ csr_ea, int E) {
    int e = blockIdx.x * blockDim.x + threadIdx.x;
    if (e >= E) return;
    int pos = row_start[dst[e]] + rank[e];
    csr_src[pos] = src[e];
    *(float2*)(csr_ea + 2 * (size_t)pos) = *(const float2*)(ea + 2 * (size_t)e);
}

__global__ void k_selfloop(const int* __restrict__ row_start, const int* __restrict__ cnt,
                           int* __restrict__ csr_src, float* __restrict__ csr_ea, int n) {
    int i = blockIdx.x * blockDim.x + threadIdx.x;
    if (i >= n) return;
    int p0 = row_start[i], deg = cnt[i];
    float s0 = 0.f, s1 = 0.f;
    for (int p = p0; p < p0 + deg; ++p) {
        s0 += csr_ea[2 * (size_t)p];
        s1 += csr_ea[2 * (size_t)p + 1];
    }
    float c = fmaxf((float)deg, 1.f);
    int pl = p0 + deg;
    csr_src[pl] = i;
    csr_ea[2 * (size_t)pl] = s0 / c;
    csr_ea[2 * (size_t)pl + 1] = s1 / c;
}

// ---------------- projection (dual W, optional fused BN on input) ----------------
__launch_bounds__(256)
__global__ void k_proj64(const float* __restrict__ h,
                         const float* __restrict__ Wl, const float* __restrict__ bl,
                         const float* __restrict__ Wr, const float* __restrict__ br,
                         const double* __restrict__ stats,
                         const float* __restrict__ bng, const float* __restrict__ bnb,
                         float* __restrict__ xl, float* __restrict__ xr, int n) {
    __shared__ float wsl[4096], wsr[4096], bna[64], bnbb[64];
    int t = threadIdx.x;
    for (int i = t; i < 4096; i += 256) { wsl[i] = Wl[i]; wsr[i] = Wr[i]; }
    const bool bn = (stats != nullptr);
    if (bn && t < 64) {
        double mu = stats[t] / n;
        double var = stats[64 + t] / n - mu * mu;
        float rs = (float)(1.0 / sqrt(var + 1e-5));
        float a = rs * bng[t];
        bna[t] = a;
        bnbb[t] = bnb[t] - (float)mu * a;
    }
    __syncthreads();
    int rg = t >> 2, cg4 = (t & 3) << 4;
    int r0 = blockIdx.x * 128 + rg * 2;
    float accl[2][16], accr[2][16];
#pragma unroll
    for (int r = 0; r < 2; ++r)
#pragma unroll
        for (int j = 0; j < 16; ++j) { accl[r][j] = 0.f; accr[r][j] = 0.f; }
    for (int k0 = 0; k0 < 64; k0 += 4) {
        float hk[2][4];
#pragma unroll
        for (int r = 0; r < 2; ++r) {
            int gr = r0 + r;
            float4 v = (gr < n) ? *(const float4*)(h + (size_t)gr * 64 + k0)
                                : make_float4(0.f, 0.f, 0.f, 0.f);
            hk[r][0] = v.x; hk[r][1] = v.y; hk[r][2] = v.z; hk[r][3] = v.w;
            if (bn) {
#pragma unroll
                for (int kk = 0; kk < 4; ++kk)
                    hk[r][kk] = lrelu(hk[r][kk] * bna[k0 + kk] + bnbb[k0 + kk], 0.01f);
            }
        }
#pragma unroll
        for (int kk = 0; kk < 4; ++kk) {
            const float* wl = wsl + (k0 + kk) * 64 + cg4;
            const float* wr = wsr + (k0 + kk) * 64 + cg4;
#pragma unroll
            for (int r = 0; r < 2; ++r)
#pragma unroll
                for (int j = 0; j < 16; ++j) {
                    accl[r][j] += hk[r][kk] * wl[j];
                    accr[r][j] += hk[r][kk] * wr[j];
                }
        }
    }
#pragma unroll
    for (int r = 0; r < 2; ++r) {
        int gr = r0 + r;
        if (gr < n) {
            float* ol = xl + (size_t)gr * 64 + cg4;
            float* orr = xr + (size_t)gr * 64 + cg4;
#pragma unroll
            for (int j = 0; j < 16; ++j) {
                ol[j] = accl[r][j] + bl[cg4 + j];
                orr[j] = accr[r][j] + br[cg4 + j];
            }
        }
    }
}

// final projections fused: packed[i][0:16)=f_xl, [16:32)=s_xl, [32:48)=f_xr, [48:64)=s_xr
__launch_bounds__(256)
__global__ void k_proj_final(const float* __restrict__ h,
                             const float* __restrict__ fWl, const float* __restrict__ fbl,
                             const float* __restrict__ fWr, const float* __restrict__ fbr,
                             const float* __restrict__ sWl, const float* __restrict__ sbl,
                             const float* __restrict__ sWr, const float* __restrict__ sbr,
                             float* __restrict__ packed, int n) {
    __shared__ float ws[4096];
    __shared__ float bs[64];
    int t = threadIdx.x;
    for (int i = t; i < 1024; i += 256) {
        int k = i >> 4, j = i & 15;
        ws[k * 64 + j] = fWl[i];
        ws[k * 64 + 16 + j] = sWl[i];
        ws[k * 64 + 32 + j] = fWr[i];
        ws[k * 64 + 48 + j] = sWr[i];
    }
    if (t < 16) { bs[t] = fbl[t]; bs[16 + t] = sbl[t]; bs[32 + t] = fbr[t]; bs[48 + t] = sbr[t]; }
    __syncthreads();
    int rg = t >> 2, cg4 = (t & 3) << 4;
    int r0 = blockIdx.x * 256 + rg * 4;
    float acc[4][16];
#pragma unroll
    for (int r = 0; r < 4; ++r)
#pragma unroll
        for (int j = 0; j < 16; ++j) acc[r][j] = 0.f;
    for (int k0 = 0; k0 < 64; k0 += 4) {
        float hk[4][4];
#pragma unroll
        for (int r = 0; r < 4; ++r) {
            int gr = r0 + r;
            float4 v = (gr < n) ? *(const float4*)(h + (size_t)gr * 64 + k0)
                                : make_float4(0.f, 0.f, 0.f, 0.f);
            hk[r][0] = v.x; hk[r][1] = v.y; hk[r][2] = v.z; hk[r][3] = v.w;
        }
#pragma unroll
        for (int kk = 0; kk < 4; ++kk) {
            const float* wrow = ws + (k0 + kk) * 64 + cg4;
#pragma unroll
            for (int r = 0; r < 4; ++r)
#pragma unroll
                for (int j = 0; j < 16; ++j) acc[r][j] += hk[r][kk] * wrow[j];
        }
    }
#pragma unroll
    for (int r = 0; r < 4; ++r) {
        int gr = r0 + r;
        if (gr < n) {
            float* o = packed + (size_t)gr * 64 + cg4;
#pragma unroll
            for (int j = 0; j < 16; ++j) o[j] = acc[r][j] + bs[cg4 + j];
        }
    }
}

// ---------------- GATv2 attention ----------------
// one wave per dst; lane = head*4 + channel. online softmax, unroll-4, 2 chains.
__launch_bounds__(256)
__global__ void k_gat(const float* __restrict__ xl, const float* __restrict__ xr,
                      const int* __restrict__ row_start, const int* __restrict__ cnt,
                      const int* __restrict__ csr_src, const float* __restrict__ csr_ea,
                      const float* __restrict__ We, const float* __restrict__ att,
                      const float* __restrict__ bias,
                      float* __restrict__ out, int n, int relu) {
    int wave = (blockIdx.x * blockDim.x + threadIdx.x) >> 6;
    int lane = threadIdx.x & 63;
    if (wave >= n) return;
    const int d = wave;
    const int p0 = __builtin_amdgcn_readfirstlane(row_start[d]);
    const int p1 = p0 + __builtin_amdgcn_readfirstlane(cnt[d]) + 1;
    const float we0 = We[lane], we1 = We[64 + lane];
    const float av = att[lane];
    const float xrv = xr[(size_t)d * 64 + lane];

    float mx0 = -3.0e38f, den0 = 0.f, acc0 = 0.f;
    float mx1 = -3.0e38f, den1 = 0.f, acc1 = 0.f;

    auto step = [&](float xv, float2 ea, bool valid, float& mx, float& den, float& acc) {
        float tv = lrelu(xv + xrv + ea.x * we0 + ea.y * we1, 0.2f) * av;
        tv += __shfl_xor(tv, 1);
        tv += __shfl_xor(tv, 2);
        if (!valid) tv = -__builtin_inff();
        float nm = fmaxf(mx, tv);
        float sc = __expf(mx - nm), w = __expf(tv - nm);
        den = den * sc + w;
        acc = acc * sc + w * xv;
        mx = nm;
    };

    for (int p = p0; p < p1; p += 4) {
        int q1 = min(p + 1, p1 - 1), q2 = min(p + 2, p1 - 1), q3 = min(p + 3, p1 - 1);
        int s0 = csr_src[p], s1 = csr_src[q1], s2 = csr_src[q2], s3 = csr_src[q3];
        float2 e0 = *(const float2*)(csr_ea + 2 * (size_t)p);
        float2 e1 = *(const float2*)(csr_ea + 2 * (size_t)q1);
        float2 e2 = *(const float2*)(csr_ea + 2 * (size_t)q2);
        float2 e3 = *(const float2*)(csr_ea + 2 * (size_t)q3);
        float x0 = xl[(size_t)s0 * 64 + lane];
        float x1 = xl[(size_t)s1 * 64 + lane];
        float x2 = xl[(size_t)s2 * 64 + lane];
        float x3 = xl[(size_t)s3 * 64 + lane];
        step(x0, e0, true, mx0, den0, acc0);
        step(x1, e1, p + 1 < p1, mx1, den1, acc1);
        step(x2, e2, p + 2 < p1, mx0, den0, acc0);
        step(x3, e3, p + 3 < p1, mx1, den1, acc1);
    }
    float nm = fmaxf(mx0, mx1);
    float sc0 = __expf(mx0 - nm), sc1 = __expf(mx1 - nm);
    float o = (acc0 * sc0 + acc1 * sc1) / (den0 * sc0 + den1 * sc1) + bias[lane];
    if (relu) o = lrelu(o, 0.01f);
    out[(size_t)d * 64 + lane] = o;
}

// final two H=16,C=1 layers fused: half-wave per dst (0-15 f -> fin, 16-31 s -> mus)
__launch_bounds__(256)
__global__ void k_gat_final(const float* __restrict__ packed,
                            const int* __restrict__ row_start, const int* __restrict__ cnt,
                            const int* __restrict__ csr_src, const float* __restrict__ csr_ea,
                            const float* __restrict__ fWe, const float* __restrict__ sWe,
                            const float* __restrict__ fatt, const float* __restrict__ satt,
                            const float* __restrict__ fbias, const float* __restrict__ sbias,
                            float* __restrict__ fin, float* __restrict__ mus, int n) {
    int hw = (blockIdx.x * blockDim.x + threadIdx.x) >> 5;
    if (hw >= n) return;
    int l = threadIdx.x & 31;
    int hh = l & 15, sel = l >> 4;
    const int d = hw;
    const int p0 = row_start[d], p1 = p0 + cnt[d] + 1;
    const float* We = sel ? sWe : fWe;
    float we0 = We[hh], we1 = We[16 + hh];
    float av = (sel ? satt : fatt)[hh];
    float xrv = packed[(size_t)d * 64 + 32 + sel * 16 + hh];
    int xli = sel * 16 + hh;

    float mx0 = -3.0e38f, den0 = 0.f, acc0 = 0.f;
    float mx1 = -3.0e38f, den1 = 0.f, acc1 = 0.f;

    auto step = [&](float xv, float2 ea, bool valid, float& mx, float& den, float& acc) {
        float t = lrelu(xv + xrv + ea.x * we0 + ea.y * we1, 0.2f) * av;
        if (!valid) t = -__builtin_inff();
        float nm = fmaxf(mx, t);
        float sc = __expf(mx - nm), w = __expf(t - nm);
        den = den * sc + w;
        acc = acc * sc + w * xv;
        mx = nm;
    };

    for (int p = p0; p < p1; p += 4) {
        int q1 = min(p + 1, p1 - 1), q2 = min(p + 2, p1 - 1), q3 = min(p + 3, p1 - 1);
        int s0 = csr_src[p], s1 = csr_src[q1], s2 = csr_src[q2], s3 = csr_src[q3];
        float2 e0 = *(const float2*)(csr_ea + 2 * (size_t)p);
        float2 e1 = *(const float2*)(csr_ea + 2 * (size_t)q1);
        float2 e2 = *(const float2*)(csr_ea + 2 * (size_t)q2);
        float2 e3 = *(const float2*)(csr_ea + 2 * (size_t)q3);
        float x0 = packed[(size_t)s0 * 64 + xli];
        float x1 = packed[(size_t)s1 * 64 + xli];
        float x2 = packed[(size_t)s2 * 64 + xli];
        float x3 = packed[(size_t)s3 * 64 + xli];
        step(x0, e0, true, mx0, den0, acc0);
        step(x1, e1, p + 1 < p1, mx1, den1, acc1);
        step(x2, e2, p + 2 < p1, mx0, den0, acc0);
        step(x3, e3, p + 3 < p1, mx1, den1, acc1);
    }
    float nm = fmaxf(mx0, mx1);
    float s0 = __expf(mx0 - nm), s1 = __expf(mx1 - nm);
    float val = (acc0 * s0 + acc1 * s1) / (den0 * s0 + den1 * s1);
#pragma unroll
    for (int w = 1; w < 16; w <<= 1) val += __shfl_xor(val, w);
    if ((threadIdx.x & 15) == 0) {
        float o = val * (1.f / 16.f) + (sel ? sbias[0] : fbias[0]);
        if (sel) mus[d] = o; else fin[d] = o;
    }
}

// ---------------- batchnorm stats ----------------

__global__ void k_bnstats(const float* __restrict__ h, double* __restrict__ stats, int n) {
    int c = threadIdx.x & 63;
    int s0 = blockIdx.x * (blockDim.x >> 6) + (threadIdx.x >> 6);
    int ns = gridDim.x * (blockDim.x >> 6);
    double s = 0.0, s2 = 0.0;
    for (int i = s0; i < n; i += ns) {
        float v = h[(size_t)i * 64 + c];
        s += v;
        s2 += (double)v * v;
    }
    atomicAdd(&stats[c], s);
    atomicAdd(&stats[64 + c], s2);
}

// ---------------- graph-level mean over masked nodes ----------------

__global__ void k_sat_acc(const float* __restrict__ fin, const int* __restrict__ mask,
                          const int* __restrict__ batch,
                          float* __restrict__ sums, float* __restrict__ cnts, int n) {
    int i = blockIdx.x * blockDim.x + threadIdx.x;
    int lane = threadIdx.x & 63;
    int g = (i < n) ? batch[i] : -1;
    float c = (i < n && mask[i] == 0) ? 1.f : 0.f;
    float v = (c > 0.f) ? fin[i] : 0.f;
#pragma unroll
    for (int off = 1; off < 64; off <<= 1) {
        float v2 = __shfl_down(v, off);
        float c2 = __shfl_down(c, off);
        int g2 = __shfl_down(g, off);
        if (lane + off < 64 && g2 == g) { v += v2; c += c2; }
    }
    int gprev = __shfl_up(g, 1);
    bool head = (lane == 0) || (gprev != g);
    if (head && g >= 0 && c > 0.f) {
        atomicAdd(&sums[g], v);
        atomicAdd(&cnts[g], c);
    }
}

__global__ void k_sat_fin(const float* __restrict__ sums, const float* __restrict__ cnts,
                          float* __restrict__ out, int g) {
    int i = threadIdx.x;
    if (i < g) out[i] = sums[i] / fmaxf(cnts[i], 1.f);
}

// ---------------- host ----------------

extern "C" void kernel_launch(void* const* d_in, const int* in_sizes, int n_in,
                              void* d_out, int out_size, void* d_ws, size_t ws_size,
                              hipStream_t stream) {
    const float* x = (const float*)d_in[0];
    const float* eat = (const float*)d_in[1];
    const int* ei = (const int*)d_in[2];
    const int* mask = (const int*)d_in[3];
    const int* batch = (const int*)d_in[4];
    const float* g0_Wl = (const float*)d_in[5];
    const float* g0_bl = (const float*)d_in[6];
    const float* g0_Wr = (const float*)d_in[7];
    const float* g0_br = (const float*)d_in[8];
    const float* g0_We = (const float*)d_in[9];
    const float* g0_att = (const float*)d_in[10];
    const float* g0_bias = (const float*)d_in[11];
    const float* bn_g = (const float*)d_in[12];
    const float* bn_b = (const float*)d_in[13];
    const float* m_Wl = (const float*)d_in[14];
    const float* m_bl = (const float*)d_in[15];
    const float* m_Wr = (const float*)d_in[16];
    const float* m_br = (const float*)d_in[17];
    const float* m_We = (const float*)d_in[18];
    const float* m_att = (const float*)d_in[19];
    const float* m_bias = (const float*)d_in[20];
    const float* f_Wl = (const float*)d_in[21];
    const float* f_bl = (const float*)d_in[22];
    const float* f_Wr = (const float*)d_in[23];
    const float* f_br = (const float*)d_in[24];
    const float* f_We = (const float*)d_in[25];
    const float* f_att = (const float*)d_in[26];
    const float* f_bias = (const float*)d_in[27];
    const float* s_Wl = (const float*)d_in[28];
    const float* s_bl = (const float*)d_in[29];
    const float* s_Wr = (const float*)d_in[30];
    const float* s_br = (const float*)d_in[31];
    const float* s_We = (const float*)d_in[32];
    const float* s_att = (const float*)d_in[33];
    const float* s_bias = (const float*)d_in[34];

    const int N = in_sizes[3];
    const int E = in_sizes[1] / 2;
    const int G = out_size - N;
    const int ITER = in_sizes[14] / 4096;
    const int ET = E + N;
    const int* srcp = ei;
    const int* dstp = ei + E;

    char* wsb = (char*)d_ws;
    size_t off = 0;
    auto alloc = [&](size_t b) { void* p = wsb + off; off = (off + b + 255) & ~(size_t)255; return p; };
    int* cnt = (int*)alloc((size_t)N * 4);
    int* cursor = (int*)alloc(256);
    double* stats = (double*)alloc(128 * 8);
    float* sums = (float*)alloc((size_t)G * 4);
    float* cnts = (float*)alloc((size_t)G * 4);
    size_t zero_bytes = off;
    int* rank = (int*)alloc((size_t)E * 4);
    int* row_start = (int*)alloc((size_t)N * 4);
    int* csr_src = (int*)alloc((size_t)ET * 4);
    float* csr_ea = (float*)alloc((size_t)ET * 8);
    float* xl = (float*)alloc((size_t)N * 256);
    float* xr = (float*)alloc((size_t)N * 256);
    float* hbuf = (float*)alloc((size_t)N * 256);
    float* fin = (float*)alloc((size_t)N * 4);
    (void)ws_size; (void)n_in;

    float* outv = (float*)d_out;  // [0,N) = mus, [N,N+G) = sat

    hipMemsetAsync(d_ws, 0, zero_bytes, stream);
    const int tb = 256;
    k_build0<<<(E + N * 64 + tb - 1) / tb, tb, 0, stream>>>(dstp, cnt, rank, E,
                                                            x, g0_Wl, g0_bl, g0_Wr, g0_br,
                                                            xl, xr, N);
    k_segoff<<<(N + tb - 1) / tb, tb, 0, stream>>>(cnt, row_start, cursor, N);
    k_scatter<<<(E + tb - 1) / tb, tb, 0, stream>>>(srcp, dstp, eat, rank, row_start,
                                                    csr_src, csr_ea, E);
    k_selfloop<<<(N + tb - 1) / tb, tb, 0, stream>>>(row_start, cnt, csr_src, csr_ea, N);

    k_gat<<<(N * 64 + tb - 1) / tb, tb, 0, stream>>>(xl, xr, row_start, cnt, csr_src, csr_ea,
                                                     g0_We, g0_att, g0_bias, hbuf, N, 0);
    k_bnstats<<<128, 256, 0, stream>>>(hbuf, stats, N);

    int gp = (N + 127) / 128;
    for (int l = 0; l < ITER; ++l) {
        k_proj64<<<gp, 256, 0, stream>>>(hbuf, m_Wl + (size_t)l * 4096, m_bl + l * 64,
                                         m_Wr + (size_t)l * 4096, m_br + l * 64,
                                         (l == 0) ? stats : nullptr, bn_g, bn_b,
                                         xl, xr, N);
        k_gat<<<(N * 64 + tb - 1) / tb, tb, 0, stream>>>(xl, xr, row_start, cnt, csr_src, csr_ea,
                                                         m_We + l * 128, m_att + l * 64,
                                                         m_bias + l * 64, hbuf, N, 1);
    }
    k_proj_final<<<(N + 255) / 256, 256, 0, stream>>>(hbuf, f_Wl, f_bl, f_Wr, f_br,
                                                      s_Wl, s_bl, s_Wr, s_br, xl, N);
    k_gat_final<<<(N * 32 + tb - 1) / tb, tb, 0, stream>>>(xl, row_start, cnt, csr_src, csr_ea,
                                                           f_We, s_We, f_att, s_att,
                                                           f_bias, s_bias, fin, outv, N);
    k_sat_acc<<<(N + tb - 1) / tb, tb, 0, stream>>>(fin, mask, batch, sums, cnts, N);
    k_sat_fin<<<1, 64, 0, stream>>>(sums, cnts, outv + N, G);
}

// Round 10
// 675.133 us; speedup vs baseline: 3.4244x; 1.1031x over previous
//
#include <hip/hip_runtime.h>

// GATv2 stack on MI355X. fp32 throughout (no fp32 MFMA on CDNA4 -> vector ALU).
// R9: fuse the (row-local) next-layer projection into the gat kernel epilogue
// via shuffle-broadcast matvec -- removes 11 proj dispatches + their gaps and
// the intermediate h write/read (-12.8MB/layer). xl/xr double-buffered.

static __device__ __forceinline__ float lrelu(float x, float s) {
    return x > 0.f ? x : s * x;
}

// ---------------- fused degree + proj0 ----------------
__global__ void k_build0(const int* __restrict__ dst, int* __restrict__ cnt,
                         int* __restrict__ rank, int E,
                         const float* __restrict__ x,
                         const float* __restrict__ Wl, const float* __restrict__ bl,
                         const float* __restrict__ Wr, const float* __restrict__ br,
                         float* __restrict__ xl, float* __restrict__ xr, int n) {
    int idx = blockIdx.x * blockDim.x + threadIdx.x;
    if (idx < E) {
        rank[idx] = atomicAdd(&cnt[dst[idx]], 1);
    } else {
        int t = idx - E;
        if (t < n * 64) {
            int i = t >> 6, c = t & 63;
            float x0 = x[2 * i], x1 = x[2 * i + 1];
            xl[t] = x0 * Wl[c] + x1 * Wl[64 + c] + bl[c];
            xr[t] = x0 * Wr[c] + x1 * Wr[64 + c] + br[c];
        }
    }
}

// wave-aggregated segment offset allocation
__global__ void k_segoff(const int* __restrict__ cnt, int* __restrict__ row_start,
                         int* __restrict__ cursor, int n) {
    int i = blockIdx.x * blockDim.x + threadIdx.x;
    int lane = threadIdx.x & 63;
    int v = (i < n) ? cnt[i] + 1 : 0;
    int s = v;
#pragma unroll
    for (int off = 1; off < 64; off <<= 1) {
        int t = __shfl_up(s, off);
        if (lane >= off) s += t;
    }
    int wavetot = __shfl(s, 63);
    int base = 0;
    if (lane == 63) base = atomicAdd(cursor, wavetot);
    base = __shfl(base, 63);
    if (i < n) row_start[i] = base + s - v;
}

__global__ void k_scatter(const int* __restrict__ src, const int* __restrict__ dst,
                          const float* __restrict__ ea, const int* __restrict__ rank,
                          const int* __restrict__ row_start,
                          int* __restrict__ csr_src, float* __restrict__ csr_ea, int E) {
    int e = blockIdx.x * blockDim.x + threadIdx.x;
    if (e >= E) return;
    int pos = row_start[dst[e]] + rank[e];
    csr_src[pos] = src[e];
    *(float2*)(csr_ea + 2 * (size_t)pos) = *(const float2*)(ea + 2 * (size_t)e);
}

__global__ void k_selfloop(const int* __restrict__ row_start, const int* __restrict__ cnt,
                           int* __restrict__ csr_src, float* __restrict__ csr_ea, int n) {
    int i = blockIdx.x * blockDim.x + threadIdx.x;
    if (i >= n) return;
    int p0 = row_start[i], deg = cnt[i];
    float s0 = 0.f, s1 = 0.f;
    for (int p = p0; p < p0 + deg; ++p) {
        s0 += csr_ea[2 * (size_t)p];
        s1 += csr_ea[2 * (size_t)p + 1];
    }
    float c = fmaxf((float)deg, 1.f);
    int pl = p0 + deg;
    csr_src[pl] = i;
    csr_ea[2 * (size_t)pl] = s0 / c;
    csr_ea[2 * (size_t)pl + 1] = s1 / c;
}

// ---------------- layer-0 projection with fused BN (reads hbuf) ----------------
__launch_bounds__(256)
__global__ void k_proj64(const float* __restrict__ h,
                         const float* __restrict__ Wl, const float* __restrict__ bl,
                         const float* __restrict__ Wr, const float* __restrict__ br,
                         const double* __restrict__ stats,
                         const float* __restrict__ bng, const float* __restrict__ bnb,
                         float* __restrict__ xl, float* __restrict__ xr, int n) {
    __shared__ float wsl[4096], wsr[4096], bna[64], bnbb[64];
    int t = threadIdx.x;
    for (int i = t; i < 4096; i += 256) { wsl[i] = Wl[i]; wsr[i] = Wr[i]; }
    if (t < 64) {
        double mu = stats[t] / n;
        double var = stats[64 + t] / n - mu * mu;
        float rs = (float)(1.0 / sqrt(var + 1e-5));
        float a = rs * bng[t];
        bna[t] = a;
        bnbb[t] = bnb[t] - (float)mu * a;
    }
    __syncthreads();
    int rg = t >> 2, cg4 = (t & 3) << 4;
    int r0 = blockIdx.x * 128 + rg * 2;
    float accl[2][16], accr[2][16];
#pragma unroll
    for (int r = 0; r < 2; ++r)
#pragma unroll
        for (int j = 0; j < 16; ++j) { accl[r][j] = 0.f; accr[r][j] = 0.f; }
    for (int k0 = 0; k0 < 64; k0 += 4) {
        float hk[2][4];
#pragma unroll
        for (int r = 0; r < 2; ++r) {
            int gr = r0 + r;
            float4 v = (gr < n) ? *(const float4*)(h + (size_t)gr * 64 + k0)
                                : make_float4(0.f, 0.f, 0.f, 0.f);
            hk[r][0] = v.x; hk[r][1] = v.y; hk[r][2] = v.z; hk[r][3] = v.w;
#pragma unroll
            for (int kk = 0; kk < 4; ++kk)
                hk[r][kk] = lrelu(hk[r][kk] * bna[k0 + kk] + bnbb[k0 + kk], 0.01f);
        }
#pragma unroll
        for (int kk = 0; kk < 4; ++kk) {
            const float* wl = wsl + (k0 + kk) * 64 + cg4;
            const float* wr = wsr + (k0 + kk) * 64 + cg4;
#pragma unroll
            for (int r = 0; r < 2; ++r)
#pragma unroll
                for (int j = 0; j < 16; ++j) {
                    accl[r][j] += hk[r][kk] * wl[j];
                    accr[r][j] += hk[r][kk] * wr[j];
                }
        }
    }
#pragma unroll
    for (int r = 0; r < 2; ++r) {
        int gr = r0 + r;
        if (gr < n) {
            float* ol = xl + (size_t)gr * 64 + cg4;
            float* orr = xr + (size_t)gr * 64 + cg4;
#pragma unroll
            for (int j = 0; j < 16; ++j) {
                ol[j] = accl[r][j] + bl[cg4 + j];
                orr[j] = accr[r][j] + br[cg4 + j];
            }
        }
    }
}

// ---------------- gat node body (shared) ----------------
// returns the post-aggregation value for (node d, channel lane); h-relu applied if relu!=0
__device__ __forceinline__ float gat_node(const float* __restrict__ xl,
                                          const float* __restrict__ xr,
                                          const int* __restrict__ row_start,
                                          const int* __restrict__ cnt,
                                          const int* __restrict__ csr_src,
                                          const float* __restrict__ csr_ea,
                                          const float* __restrict__ We,
                                          const float* __restrict__ att,
                                          const float* __restrict__ bias,
                                          int d, int lane, int relu) {
    const int p0 = __builtin_amdgcn_readfirstlane(row_start[d]);
    const int p1 = p0 + __builtin_amdgcn_readfirstlane(cnt[d]) + 1;
    const float we0 = We[lane], we1 = We[64 + lane];
    const float av = att[lane];
    const float xrv = xr[(size_t)d * 64 + lane];

    float mx0 = -3.0e38f, den0 = 0.f, acc0 = 0.f;
    float mx1 = -3.0e38f, den1 = 0.f, acc1 = 0.f;

    auto step = [&](float xv, float2 ea, bool valid, float& mx, float& den, float& acc) {
        float tv = lrelu(xv + xrv + ea.x * we0 + ea.y * we1, 0.2f) * av;
        tv += __shfl_xor(tv, 1);
        tv += __shfl_xor(tv, 2);
        if (!valid) tv = -__builtin_inff();
        float nm = fmaxf(mx, tv);
        float sc = __expf(mx - nm), w = __expf(tv - nm);
        den = den * sc + w;
        acc = acc * sc + w * xv;
        mx = nm;
    };

    for (int p = p0; p < p1; p += 4) {
        int q1 = min(p + 1, p1 - 1), q2 = min(p + 2, p1 - 1), q3 = min(p + 3, p1 - 1);
        int s0 = csr_src[p], s1 = csr_src[q1], s2 = csr_src[q2], s3 = csr_src[q3];
        float2 e0 = *(const float2*)(csr_ea + 2 * (size_t)p);
        float2 e1 = *(const float2*)(csr_ea + 2 * (size_t)q1);
        float2 e2 = *(const float2*)(csr_ea + 2 * (size_t)q2);
        float2 e3 = *(const float2*)(csr_ea + 2 * (size_t)q3);
        float x0 = xl[(size_t)s0 * 64 + lane];
        float x1 = xl[(size_t)s1 * 64 + lane];
        float x2 = xl[(size_t)s2 * 64 + lane];
        float x3 = xl[(size_t)s3 * 64 + lane];
        step(x0, e0, true, mx0, den0, acc0);
        step(x1, e1, p + 1 < p1, mx1, den1, acc1);
        step(x2, e2, p + 2 < p1, mx0, den0, acc0);
        step(x3, e3, p + 3 < p1, mx1, den1, acc1);
    }
    float nm = fmaxf(mx0, mx1);
    float sc0 = __expf(mx0 - nm), sc1 = __expf(mx1 - nm);
    float o = (acc0 * sc0 + acc1 * sc1) / (den0 * sc0 + den1 * sc1) + bias[lane];
    if (relu) o = lrelu(o, 0.01f);
    return o;
}

// plain gat (layer 0 -> hbuf, no relu)
__launch_bounds__(256)
__global__ void k_gat(const float* __restrict__ xl, const float* __restrict__ xr,
                      const int* __restrict__ row_start, const int* __restrict__ cnt,
                      const int* __restrict__ csr_src, const float* __restrict__ csr_ea,
                      const float* __restrict__ We, const float* __restrict__ att,
                      const float* __restrict__ bias,
                      float* __restrict__ out, int n, int relu) {
    int wave = (blockIdx.x * blockDim.x + threadIdx.x) >> 6;
    int lane = threadIdx.x & 63;
    if (wave >= n) return;
    float o = gat_node(xl, xr, row_start, cnt, csr_src, csr_ea, We, att, bias, wave, lane, relu);
    out[(size_t)wave * 64 + lane] = o;
}

// gat + fused next-layer dual projection epilogue (middle layers)
__launch_bounds__(256)
__global__ void k_gat_proj(const float* __restrict__ xl, const float* __restrict__ xr,
                           const int* __restrict__ row_start, const int* __restrict__ cnt,
                           const int* __restrict__ csr_src, const float* __restrict__ csr_ea,
                           const float* __restrict__ We, const float* __restrict__ att,
                           const float* __restrict__ bias,
                           const float* __restrict__ Wnl, const float* __restrict__ bnl,
                           const float* __restrict__ Wnr, const float* __restrict__ bnr,
                           float* __restrict__ xl_out, float* __restrict__ xr_out, int n) {
    int wave = (blockIdx.x * blockDim.x + threadIdx.x) >> 6;
    int lane = threadIdx.x & 63;
    if (wave >= n) return;
    const int d = wave;
    float o = gat_node(xl, xr, row_start, cnt, csr_src, csr_ea, We, att, bias, d, lane, 1);
    // shuffle-broadcast matvec: xl_out[d][lane] = sum_k o_k * Wnl[k][lane] + bnl
    float a0 = 0.f, a1 = 0.f, b0 = 0.f, b1 = 0.f;
#pragma unroll 8
    for (int k = 0; k < 64; k += 2) {
        float h0 = __shfl(o, k);
        float h1 = __shfl(o, k + 1);
        a0 += h0 * Wnl[k * 64 + lane];
        a1 += h1 * Wnl[(k + 1) * 64 + lane];
        b0 += h0 * Wnr[k * 64 + lane];
        b1 += h1 * Wnr[(k + 1) * 64 + lane];
    }
    xl_out[(size_t)d * 64 + lane] = a0 + a1 + bnl[lane];
    xr_out[(size_t)d * 64 + lane] = b0 + b1 + bnr[lane];
}

// gat + fused FINAL packed projection epilogue (last main layer)
// packed[d] = [f_xl(16) | s_xl(16) | f_xr(16) | s_xr(16)]
__launch_bounds__(256)
__global__ void k_gat_projfin(const float* __restrict__ xl, const float* __restrict__ xr,
                              const int* __restrict__ row_start, const int* __restrict__ cnt,
                              const int* __restrict__ csr_src, const float* __restrict__ csr_ea,
                              const float* __restrict__ We, const float* __restrict__ att,
                              const float* __restrict__ bias,
                              const float* __restrict__ fWl, const float* __restrict__ fbl,
                              const float* __restrict__ fWr, const float* __restrict__ fbr,
                              const float* __restrict__ sWl, const float* __restrict__ sbl,
                              const float* __restrict__ sWr, const float* __restrict__ sbr,
                              float* __restrict__ packed, int n) {
    int wave = (blockIdx.x * blockDim.x + threadIdx.x) >> 6;
    int lane = threadIdx.x & 63;
    if (wave >= n) return;
    const int d = wave;
    float o = gat_node(xl, xr, row_start, cnt, csr_src, csr_ea, We, att, bias, d, lane, 1);
    int q = lane >> 4, cc = lane & 15;
    const float* W = (q == 0) ? fWl : (q == 1) ? sWl : (q == 2) ? fWr : sWr;
    const float* B = (q == 0) ? fbl : (q == 1) ? sbl : (q == 2) ? fbr : sbr;
    float a0 = 0.f, a1 = 0.f;
#pragma unroll 8
    for (int k = 0; k < 64; k += 2) {
        a0 += __shfl(o, k) * W[k * 16 + cc];
        a1 += __shfl(o, k + 1) * W[(k + 1) * 16 + cc];
    }
    packed[(size_t)d * 64 + lane] = a0 + a1 + B[cc];
}

// final two H=16,C=1 layers fused: half-wave per dst (0-15 f -> fin, 16-31 s -> mus)
__launch_bounds__(256)
__global__ void k_gat_final(const float* __restrict__ packed,
                            const int* __restrict__ row_start, const int* __restrict__ cnt,
                            const int* __restrict__ csr_src, const float* __restrict__ csr_ea,
                            const float* __restrict__ fWe, const float* __restrict__ sWe,
                            const float* __restrict__ fatt, const float* __restrict__ satt,
                            const float* __restrict__ fbias, const float* __restrict__ sbias,
                            float* __restrict__ fin, float* __restrict__ mus, int n) {
    int hw = (blockIdx.x * blockDim.x + threadIdx.x) >> 5;
    if (hw >= n) return;
    int l = threadIdx.x & 31;
    int hh = l & 15, sel = l >> 4;
    const int d = hw;
    const int p0 = row_start[d], p1 = p0 + cnt[d] + 1;
    const float* We = sel ? sWe : fWe;
    float we0 = We[hh], we1 = We[16 + hh];
    float av = (sel ? satt : fatt)[hh];
    float xrv = packed[(size_t)d * 64 + 32 + sel * 16 + hh];
    int xli = sel * 16 + hh;

    float mx0 = -3.0e38f, den0 = 0.f, acc0 = 0.f;
    float mx1 = -3.0e38f, den1 = 0.f, acc1 = 0.f;

    auto step = [&](float xv, float2 ea, bool valid, float& mx, float& den, float& acc) {
        float t = lrelu(xv + xrv + ea.x * we0 + ea.y * we1, 0.2f) * av;
        if (!valid) t = -__builtin_inff();
        float nm = fmaxf(mx, t);
        float sc = __expf(mx - nm), w = __expf(t - nm);
        den = den * sc + w;
        acc = acc * sc + w * xv;
        mx = nm;
    };

    for (int p = p0; p < p1; p += 4) {
        int q1 = min(p + 1, p1 - 1), q2 = min(p + 2, p1 - 1), q3 = min(p + 3, p1 - 1);
        int s0 = csr_src[p], s1 = csr_src[q1], s2 = csr_src[q2], s3 = csr_src[q3];
        float2 e0 = *(const float2*)(csr_ea + 2 * (size_t)p);
        float2 e1 = *(const float2*)(csr_ea + 2 * (size_t)q1);
        float2 e2 = *(const float2*)(csr_ea + 2 * (size_t)q2);
        float2 e3 = *(const float2*)(csr_ea + 2 * (size_t)q3);
        float x0 = packed[(size_t)s0 * 64 + xli];
        float x1 = packed[(size_t)s1 * 64 + xli];
        float x2 = packed[(size_t)s2 * 64 + xli];
        float x3 = packed[(size_t)s3 * 64 + xli];
        step(x0, e0, true, mx0, den0, acc0);
        step(x1, e1, p + 1 < p1, mx1, den1, acc1);
        step(x2, e2, p + 2 < p1, mx0, den0, acc0);
        step(x3, e3, p + 3 < p1, mx1, den1, acc1);
    }
    float nm = fmaxf(mx0, mx1);
    float s0 = __expf(mx0 - nm), s1 = __expf(mx1 - nm);
    float val = (acc0 * s0 + acc1 * s1) / (den0 * s0 + den1 * s1);
#pragma unroll
    for (int w = 1; w < 16; w <<= 1) val += __shfl_xor(val, w);
    if ((threadIdx.x & 15) == 0) {
        float o = val * (1.f / 16.f) + (sel ? sbias[0] : fbias[0]);
        if (sel) mus[d] = o; else fin[d] = o;
    }
}

// ---------------- batchnorm stats ----------------

__global__ void k_bnstats(const float* __restrict__ h, double* __restrict__ stats, int n) {
    int c = threadIdx.x & 63;
    int s0 = blockIdx.x * (blockDim.x >> 6) + (threadIdx.x >> 6);
    int ns = gridDim.x * (blockDim.x >> 6);
    double s = 0.0, s2 = 0.0;
    for (int i = s0; i < n; i += ns) {
        float v = h[(size_t)i * 64 + c];
        s += v;
        s2 += (double)v * v;
    }
    atomicAdd(&stats[c], s);
    atomicAdd(&stats[64 + c], s2);
}

// ---------------- graph-level mean over masked nodes ----------------

__global__ void k_sat_acc(const float* __restrict__ fin, const int* __restrict__ mask,
                          const int* __restrict__ batch,
                          float* __restrict__ sums, float* __restrict__ cnts, int n) {
    int i = blockIdx.x * blockDim.x + threadIdx.x;
    int lane = threadIdx.x & 63;
    int g = (i < n) ? batch[i] : -1;
    float c = (i < n && mask[i] == 0) ? 1.f : 0.f;
    float v = (c > 0.f) ? fin[i] : 0.f;
#pragma unroll
    for (int off = 1; off < 64; off <<= 1) {
        float v2 = __shfl_down(v, off);
        float c2 = __shfl_down(c, off);
        int g2 = __shfl_down(g, off);
        if (lane + off < 64 && g2 == g) { v += v2; c += c2; }
    }
    int gprev = __shfl_up(g, 1);
    bool head = (lane == 0) || (gprev != g);
    if (head && g >= 0 && c > 0.f) {
        atomicAdd(&sums[g], v);
        atomicAdd(&cnts[g], c);
    }
}

__global__ void k_sat_fin(const float* __restrict__ sums, const float* __restrict__ cnts,
                          float* __restrict__ out, int g) {
    int i = threadIdx.x;
    if (i < g) out[i] = sums[i] / fmaxf(cnts[i], 1.f);
}

// ---------------- host ----------------

extern "C" void kernel_launch(void* const* d_in, const int* in_sizes, int n_in,
                              void* d_out, int out_size, void* d_ws, size_t ws_size,
                              hipStream_t stream) {
    const float* x = (const float*)d_in[0];
    const float* eat = (const float*)d_in[1];
    const int* ei = (const int*)d_in[2];
    const int* mask = (const int*)d_in[3];
    const int* batch = (const int*)d_in[4];
    const float* g0_Wl = (const float*)d_in[5];
    const float* g0_bl = (const float*)d_in[6];
    const float* g0_Wr = (const float*)d_in[7];
    const float* g0_br = (const float*)d_in[8];
    const float* g0_We = (const float*)d_in[9];
    const float* g0_att = (const float*)d_in[10];
    const float* g0_bias = (const float*)d_in[11];
    const float* bn_g = (const float*)d_in[12];
    const float* bn_b = (const float*)d_in[13];
    const float* m_Wl = (const float*)d_in[14];
    const float* m_bl = (const float*)d_in[15];
    const float* m_Wr = (const float*)d_in[16];
    const float* m_br = (const float*)d_in[17];
    const float* m_We = (const float*)d_in[18];
    const float* m_att = (const float*)d_in[19];
    const float* m_bias = (const float*)d_in[20];
    const float* f_Wl = (const float*)d_in[21];
    const float* f_bl = (const float*)d_in[22];
    const float* f_Wr = (const float*)d_in[23];
    const float* f_br = (const float*)d_in[24];
    const float* f_We = (const float*)d_in[25];
    const float* f_att = (const float*)d_in[26];
    const float* f_bias = (const float*)d_in[27];
    const float* s_Wl = (const float*)d_in[28];
    const float* s_bl = (const float*)d_in[29];
    const float* s_Wr = (const float*)d_in[30];
    const float* s_br = (const float*)d_in[31];
    const float* s_We = (const float*)d_in[32];
    const float* s_att = (const float*)d_in[33];
    const float* s_bias = (const float*)d_in[34];

    const int N = in_sizes[3];
    const int E = in_sizes[1] / 2;
    const int G = out_size - N;
    const int ITER = in_sizes[14] / 4096;
    const int ET = E + N;
    const int* srcp = ei;
    const int* dstp = ei + E;

    char* wsb = (char*)d_ws;
    size_t off = 0;
    auto alloc = [&](size_t b) { void* p = wsb + off; off = (off + b + 255) & ~(size_t)255; return p; };
    int* cnt = (int*)alloc((size_t)N * 4);
    int* cursor = (int*)alloc(256);
    double* stats = (double*)alloc(128 * 8);
    float* sums = (float*)alloc((size_t)G * 4);
    float* cnts = (float*)alloc((size_t)G * 4);
    size_t zero_bytes = off;
    int* rank = (int*)alloc((size_t)E * 4);
    int* row_start = (int*)alloc((size_t)N * 4);
    int* csr_src = (int*)alloc((size_t)ET * 4);
    float* csr_ea = (float*)alloc((size_t)ET * 8);
    float* xlA = (float*)alloc((size_t)N * 256);
    float* xrA = (float*)alloc((size_t)N * 256);
    float* xlB = (float*)alloc((size_t)N * 256);
    float* xrB = (float*)alloc((size_t)N * 256);
    float* hbuf = (float*)alloc((size_t)N * 256);
    float* fin = (float*)alloc((size_t)N * 4);
    (void)ws_size; (void)n_in;

    float* outv = (float*)d_out;  // [0,N) = mus, [N,N+G) = sat

    hipMemsetAsync(d_ws, 0, zero_bytes, stream);
    const int tb = 256;
    const int ggrid = (N * 64 + tb - 1) / tb;
    k_build0<<<(E + N * 64 + tb - 1) / tb, tb, 0, stream>>>(dstp, cnt, rank, E,
                                                            x, g0_Wl, g0_bl, g0_Wr, g0_br,
                                                            xlA, xrA, N);
    k_segoff<<<(N + tb - 1) / tb, tb, 0, stream>>>(cnt, row_start, cursor, N);
    k_scatter<<<(E + tb - 1) / tb, tb, 0, stream>>>(srcp, dstp, eat, rank, row_start,
                                                    csr_src, csr_ea, E);
    k_selfloop<<<(N + tb - 1) / tb, tb, 0, stream>>>(row_start, cnt, csr_src, csr_ea, N);

    k_gat<<<ggrid, tb, 0, stream>>>(xlA, xrA, row_start, cnt, csr_src, csr_ea,
                                    g0_We, g0_att, g0_bias, hbuf, N, 0);
    k_bnstats<<<128, 256, 0, stream>>>(hbuf, stats, N);
    // BN-folded projection for main layer 0 -> buffer A
    k_proj64<<<(N + 127) / 128, 256, 0, stream>>>(hbuf, m_Wl, m_bl, m_Wr, m_br,
                                                  stats, bn_g, bn_b, xlA, xrA, N);

    float* cur_l = xlA; float* cur_r = xrA;
    float* alt_l = xlB; float* alt_r = xrB;
    for (int l = 0; l < ITER; ++l) {
        if (l < ITER - 1) {
            k_gat_proj<<<ggrid, tb, 0, stream>>>(cur_l, cur_r, row_start, cnt, csr_src, csr_ea,
                                                 m_We + l * 128, m_att + l * 64, m_bias + l * 64,
                                                 m_Wl + (size_t)(l + 1) * 4096, m_bl + (l + 1) * 64,
                                                 m_Wr + (size_t)(l + 1) * 4096, m_br + (l + 1) * 64,
                                                 alt_l, alt_r, N);
        } else {
            // last main layer: epilogue emits packed final projection into alt_l
            k_gat_projfin<<<ggrid, tb, 0, stream>>>(cur_l, cur_r, row_start, cnt, csr_src, csr_ea,
                                                    m_We + l * 128, m_att + l * 64, m_bias + l * 64,
                                                    f_Wl, f_bl, f_Wr, f_br,
                                                    s_Wl, s_bl, s_Wr, s_br,
                                                    alt_l, N);
        }
        float* t;
        t = cur_l; cur_l = alt_l; alt_l = t;
        t = cur_r; cur_r = alt_r; alt_r = t;
    }
    k_gat_final<<<(N * 32 + tb - 1) / tb, tb, 0, stream>>>(cur_l, row_start, cnt, csr_src, csr_ea,
                                                           f_We, s_We, f_att, s_att,
                                                           f_bias, s_bias, fin, outv, N);
    k_sat_acc<<<(N + tb - 1) / tb, tb, 0, stream>>>(fin, mask, batch, sums, cnts, N);
    k_sat_fin<<<1, 64, 0, stream>>>(sums, cnts, outv + N, G);
}